// Round 4
// baseline (3042.086 us; speedup 1.0000x reference)
//
#include <hip/hip_runtime.h>
#include <hip/hip_bf16.h>

typedef unsigned short u16;
typedef unsigned int u32;

#define T_TOK 43904   // 128 windows * 343 tokens
#define NTOK 343

__device__ __forceinline__ float bf2f(u32 v) { return __uint_as_float(v << 16); }
__device__ __forceinline__ u16 f2bf(float f) {
  u32 u = __float_as_uint(f);
  return (u16)((u + 0x7fffu + ((u >> 16) & 1u)) >> 16);
}

// ---- dual-dtype input loaders: f32!=0 -> data is fp32, else packed bf16 ----
__device__ __forceinline__ float ldf(const void* p, int f32, size_t i) {
  return f32 ? ((const float*)p)[i] : bf2f(((const u16*)p)[i]);
}
__device__ __forceinline__ float2 ld2(const void* p, int f32, size_t i) {  // i even
  if (f32) return *(const float2*)((const float*)p + i);
  u32 pk = *(const u32*)((const u16*)p + i);
  return make_float2(bf2f(pk & 0xffff), bf2f(pk >> 16));
}
__device__ __forceinline__ void ld8(const void* p, int f32, size_t i, float* o) {  // i%8==0
  if (f32) {
    float4 a = *(const float4*)((const float*)p + i);
    float4 b = *(const float4*)((const float*)p + i + 4);
    o[0] = a.x; o[1] = a.y; o[2] = a.z; o[3] = a.w;
    o[4] = b.x; o[5] = b.y; o[6] = b.z; o[7] = b.w;
  } else {
    uint4 pk = *(const uint4*)((const u16*)p + i);
    u32 v[4] = {pk.x, pk.y, pk.z, pk.w};
    #pragma unroll
    for (int q = 0; q < 4; q++) { o[2 * q] = bf2f(v[q] & 0xffff); o[2 * q + 1] = bf2f(v[q] >> 16); }
  }
}

// token index t (window-major) -> element offset of the (b,d,h,w) voxel in x/out
__device__ __forceinline__ size_t spatial_base(int t) {
  int win = t / 343, n = t - win * 343;
  int bb = win >> 6, wrem = win & 63;
  int wd = wrem >> 4, wh = (wrem >> 2) & 3, ww = wrem & 3;
  int td = n / 49; int r = n - td * 49; int th = r / 7; int tw = r - th * 7;
  int d0 = wd * 7 + td + 3; if (d0 >= 28) d0 -= 28;
  int h0 = wh * 7 + th + 3; if (h0 >= 28) h0 -= 28;
  int w0 = ww * 7 + tw + 3; if (w0 >= 28) w0 -= 28;
  return (size_t)(((bb * 28 + d0) * 28 + h0) * 28 + w0) * 96;
}

// ---------------- dtype detector ----------------
// bf16 N(0,1) data: every u16 decodes to |v| < 2^17. fp32 data: even u16s are
// low mantissa bits, ~44% have exponent >= 0x90. 512 samples -> certain.
__global__ __launch_bounds__(64) void detect_kernel(const u16* __restrict__ x, int* __restrict__ flag) {
  int lane = threadIdx.x;
  int bad = 0;
  #pragma unroll
  for (int q = 0; q < 8; q++) {
    u16 b = x[(lane * 8 + q) * 2];
    int e = (b >> 7) & 0xff;
    if (e >= 0x90) bad = 1;
  }
  unsigned long long m = __ballot(bad);
  if (lane == 0) *flag = (m != 0ull) ? 1 : 0;
}

// ---------------- LN1 + shift + window partition gather ----------------
__global__ __launch_bounds__(256) void ln_gather_kernel(
    const void* __restrict__ x, const void* __restrict__ g, const void* __restrict__ b,
    u16* __restrict__ outw, const int* __restrict__ dflag) {
  int f32 = __builtin_amdgcn_readfirstlane(dflag[0]);
  int t = blockIdx.x * 4 + (threadIdx.x >> 6);
  int lane = threadIdx.x & 63;
  size_t base = spatial_base(t);
  int c = lane * 2;
  float vx = 0.f, vy = 0.f;
  if (c < 96) { float2 p = ld2(x, f32, base + c); vx = p.x; vy = p.y; }
  float s = vx + vy, ss = vx * vx + vy * vy;
  #pragma unroll
  for (int o = 1; o < 64; o <<= 1) { s += __shfl_xor(s, o); ss += __shfl_xor(ss, o); }
  float mean = s * (1.f / 96.f);
  float var = ss * (1.f / 96.f) - mean * mean;
  float rstd = rsqrtf(var + 1e-5f);
  if (c < 96) {
    float2 gp = ld2(g, f32, c), bp = ld2(b, f32, c);
    float y0 = (vx - mean) * rstd * gp.x + bp.x;
    float y1 = (vy - mean) * rstd * gp.y + bp.y;
    *(u32*)(outw + (size_t)t * 96 + c) = (u32)f2bf(y0) | ((u32)f2bf(y1) << 16);
  }
}

// ---------------- LN2 (reads bf16 xres, token order) ----------------
__global__ __launch_bounds__(256) void ln2_kernel(
    const u16* __restrict__ xres, const void* __restrict__ g, const void* __restrict__ b,
    u16* __restrict__ outh, const int* __restrict__ dflag) {
  int f32 = __builtin_amdgcn_readfirstlane(dflag[0]);
  int t = blockIdx.x * 4 + (threadIdx.x >> 6);
  int lane = threadIdx.x & 63;
  int c = lane * 2;
  float vx = 0.f, vy = 0.f;
  if (c < 96) {
    u32 pk = *(const u32*)(xres + (size_t)t * 96 + c);
    vx = bf2f(pk & 0xffff); vy = bf2f(pk >> 16);
  }
  float s = vx + vy, ss = vx * vx + vy * vy;
  #pragma unroll
  for (int o = 1; o < 64; o <<= 1) { s += __shfl_xor(s, o); ss += __shfl_xor(ss, o); }
  float mean = s * (1.f / 96.f);
  float var = ss * (1.f / 96.f) - mean * mean;
  float rstd = rsqrtf(var + 1e-5f);
  if (c < 96) {
    float2 gp = ld2(g, f32, c), bp = ld2(b, f32, c);
    float y0 = (vx - mean) * rstd * gp.x + bp.x;
    float y1 = (vy - mean) * rstd * gp.y + bp.y;
    *(u32*)(outh + (size_t)t * 96 + c) = (u32)f2bf(y0) | ((u32)f2bf(y1) << 16);
  }
}

// ---------------- tiled GEMM with fused epilogues ----------------
// out[m,n] = epi(sum_k A[m,k]*W[n,k] + bias[n]).  grid=(M/64, N/32), block=128.
// A is internal bf16. W/bias are external (dual dtype).
// MODE 0: bf16 store           MODE 1: exact GELU -> bf16
// MODE 2: + x[spatial(m),n] -> bf16 xres
// MODE 3: + xres[m,n] -> store at spatial(m) in OUTPUT dtype (f32 ? fp32 : bf16)
template <int MODE>
__global__ __launch_bounds__(128) void gemm_epi_kernel(
    const u16* __restrict__ A, const void* __restrict__ W, const void* __restrict__ bias,
    const void* __restrict__ xg, const u16* __restrict__ xres,
    void* __restrict__ outp, int K, int N, const int* __restrict__ dflag) {
  int f32 = __builtin_amdgcn_readfirstlane(dflag[0]);
  __shared__ float As[64][33];
  __shared__ float Ws[32][33];
  int tid = threadIdx.x;
  int m0 = blockIdx.x * 64, n0 = blockIdx.y * 32;
  int tm = (tid & 15) * 4, tn = (tid >> 4) * 4;
  float acc[4][4] = {};
  for (int k0 = 0; k0 < K; k0 += 32) {
    {
      int m = tid >> 1, kk = (tid & 1) * 16;
      const u32* src = (const u32*)(A + (size_t)(m0 + m) * K + k0 + kk);
      #pragma unroll
      for (int q = 0; q < 8; q++) {
        u32 pk = src[q];
        As[m][kk + 2 * q] = bf2f(pk & 0xffff);
        As[m][kk + 2 * q + 1] = bf2f(pk >> 16);
      }
    }
    {
      int n = tid >> 2, kk = (tid & 3) * 8;
      float f[8];
      ld8(W, f32, (size_t)(n0 + n) * K + k0 + kk, f);
      #pragma unroll
      for (int q = 0; q < 8; q++) Ws[n][kk + q] = f[q];
    }
    __syncthreads();
    #pragma unroll
    for (int kk = 0; kk < 32; kk++) {
      float a[4], w[4];
      #pragma unroll
      for (int i = 0; i < 4; i++) a[i] = As[tm + i][kk];
      #pragma unroll
      for (int j = 0; j < 4; j++) w[j] = Ws[tn + j][kk];
      #pragma unroll
      for (int i = 0; i < 4; i++)
        #pragma unroll
        for (int j = 0; j < 4; j++) acc[i][j] = fmaf(a[i], w[j], acc[i][j]);
    }
    __syncthreads();
  }
  #pragma unroll
  for (int i = 0; i < 4; i++) {
    int mm = m0 + tm + i;
    size_t sb = (MODE >= 2) ? spatial_base(mm) : 0;
    #pragma unroll
    for (int j = 0; j < 4; j++) {
      int nn = n0 + tn + j;
      float v = acc[i][j] + ldf(bias, f32, nn);
      if (MODE == 1) v = 0.5f * v * (1.0f + erff(v * 0.70710678118f));
      if (MODE == 0 || MODE == 1) {
        ((u16*)outp)[(size_t)mm * N + nn] = f2bf(v);
      } else if (MODE == 2) {
        ((u16*)outp)[(size_t)mm * 96 + nn] = f2bf(v + ldf(xg, f32, sb + nn));
      } else {
        float r = bf2f(xres[(size_t)mm * 96 + nn]) + v;
        if (f32) ((float*)outp)[sb + nn] = r;
        else     ((u16*)outp)[sb + nn] = f2bf(r);
      }
    }
  }
}

// ---------------- fused attention: scores + bias + mask + softmax + PV ----------------
// grid = (22, 384), block = 256. blockIdx.y = wh (win*3+head), blockIdx.x = q-tile of 16.
__global__ __launch_bounds__(256) void attn_fused_kernel(
    const u16* __restrict__ qkv, const void* __restrict__ bias_table,
    const void* __restrict__ maskm, const int* __restrict__ rel_index,
    u16* __restrict__ attnb, const int* __restrict__ dflag) {
  int f32 = __builtin_amdgcn_readfirstlane(dflag[0]);
  __shared__ float qs[16][33];
  __shared__ float ks[64][33];     // K tile, later reused as V tile
  __shared__ float srow[16][345];  // 345 coprime with 32 -> conflict-free row walk
  int wh = blockIdx.y;
  int head = wh % 3;
  int win = wh / 3;
  int m0 = blockIdx.x * 16;
  size_t wbase = (size_t)win * NTOK;
  int tid = threadIdx.x;
  // q tile (pre-scaled by 1/sqrt(32))
  {
    int r = tid >> 4, c2 = (tid & 15) * 2;
    float v0 = 0.f, v1 = 0.f;
    if (m0 + r < NTOK) {
      u32 pk = *(const u32*)(qkv + (wbase + m0 + r) * 288 + head * 32 + c2);
      v0 = bf2f(pk & 0xffff) * 0.17677669529663687f;
      v1 = bf2f(pk >> 16) * 0.17677669529663687f;
    }
    qs[r][c2] = v0; qs[r][c2 + 1] = v1;
  }
  int m = tid & 15;
  int ng = tid >> 4;
  int mrow = m0 + m;
  int mclamp = mrow < NTOK ? mrow : NTOK - 1;
  const int* relrow = rel_index + mclamp * NTOK;
  size_t maskbase = ((size_t)(win & 63) * NTOK + mclamp) * NTOK;
  // ---- scores ----
  for (int k0 = 0; k0 < NTOK; k0 += 64) {
    {
      int r = tid >> 2, c8 = (tid & 3) * 8;
      float f[8];
      if (k0 + r < NTOK) {
        uint4 pk4 = *(const uint4*)(qkv + (wbase + k0 + r) * 288 + 96 + head * 32 + c8);
        u32 pv[4] = {pk4.x, pk4.y, pk4.z, pk4.w};
        #pragma unroll
        for (int q = 0; q < 4; q++) { f[2 * q] = bf2f(pv[q] & 0xffff); f[2 * q + 1] = bf2f(pv[q] >> 16); }
      } else {
        #pragma unroll
        for (int q = 0; q < 8; q++) f[q] = 0.f;
      }
      #pragma unroll
      for (int q = 0; q < 8; q++) ks[r][c8 + q] = f[q];
    }
    __syncthreads();
    float a0 = 0.f, a1 = 0.f, a2 = 0.f, a3 = 0.f;
    #pragma unroll
    for (int kk = 0; kk < 32; kk++) {
      float qv = qs[m][kk];
      a0 = fmaf(qv, ks[ng * 4 + 0][kk], a0);
      a1 = fmaf(qv, ks[ng * 4 + 1][kk], a1);
      a2 = fmaf(qv, ks[ng * 4 + 2][kk], a2);
      a3 = fmaf(qv, ks[ng * 4 + 3][kk], a3);
    }
    if (mrow < NTOK) {
      float av[4] = {a0, a1, a2, a3};
      #pragma unroll
      for (int i = 0; i < 4; i++) {
        int j = k0 + ng * 4 + i;
        if (j < NTOK)
          srow[m][j] = av[i] + ldf(bias_table, f32, (size_t)relrow[j] * 3 + head)
                             + ldf(maskm, f32, maskbase + j);
      }
    }
    __syncthreads();
  }
  // ---- softmax (16 lanes per row) ----
  {
    int rm = tid >> 4, t16 = tid & 15;
    if (m0 + rm < NTOK) {
      float mx = -1e30f;
      for (int j = t16; j < NTOK; j += 16) mx = fmaxf(mx, srow[rm][j]);
      #pragma unroll
      for (int o = 1; o < 16; o <<= 1) mx = fmaxf(mx, __shfl_xor(mx, o));
      float sum = 0.f;
      for (int j = t16; j < NTOK; j += 16) { float p = __expf(srow[rm][j] - mx); srow[rm][j] = p; sum += p; }
      #pragma unroll
      for (int o = 1; o < 16; o <<= 1) sum += __shfl_xor(sum, o);
      float rs = 1.0f / sum;
      for (int j = t16; j < NTOK; j += 16) srow[rm][j] *= rs;
    }
  }
  __syncthreads();
  // ---- PV: thread (m, ng) owns row m, cols {2ng, 2ng+1} ----
  float o0 = 0.f, o1 = 0.f;
  for (int k0 = 0; k0 < NTOK; k0 += 64) {
    {
      int r = tid >> 2, c8 = (tid & 3) * 8;
      float f[8];
      if (k0 + r < NTOK) {
        uint4 pk4 = *(const uint4*)(qkv + (wbase + k0 + r) * 288 + 192 + head * 32 + c8);
        u32 pv[4] = {pk4.x, pk4.y, pk4.z, pk4.w};
        #pragma unroll
        for (int q = 0; q < 4; q++) { f[2 * q] = bf2f(pv[q] & 0xffff); f[2 * q + 1] = bf2f(pv[q] >> 16); }
      } else {
        #pragma unroll
        for (int q = 0; q < 8; q++) f[q] = 0.f;
      }
      #pragma unroll
      for (int q = 0; q < 8; q++) ks[r][c8 + q] = f[q];
    }
    __syncthreads();
    int kmax = NTOK - k0; if (kmax > 64) kmax = 64;
    for (int kk = 0; kk < kmax; kk++) {
      float p = srow[m][k0 + kk];
      o0 = fmaf(p, ks[kk][2 * ng], o0);
      o1 = fmaf(p, ks[kk][2 * ng + 1], o1);
    }
    __syncthreads();
  }
  if (mrow < NTOK) {
    *(u32*)(attnb + (wbase + mrow) * 96 + head * 32 + 2 * ng) =
        (u32)f2bf(o0) | ((u32)f2bf(o1) << 16);
  }
}

extern "C" void kernel_launch(void* const* d_in, const int* in_sizes, int n_in,
                              void* d_out, int out_size, void* d_ws, size_t ws_size,
                              hipStream_t stream) {
  (void)in_sizes; (void)n_in; (void)out_size; (void)ws_size;
  const void* x       = d_in[0];
  const void* maskm   = d_in[1];
  const void* g1      = d_in[2];
  const void* b1      = d_in[3];
  const void* w_qkv   = d_in[4];
  const void* b_qkv   = d_in[5];
  const void* bias_tb = d_in[6];
  const void* w_proj  = d_in[7];
  const void* b_proj  = d_in[8];
  const void* g2      = d_in[9];
  const void* b2      = d_in[10];
  const void* w_fc1   = d_in[11];
  const void* b_fc1   = d_in[12];
  const void* w_fc2   = d_in[13];
  const void* b_fc2   = d_in[14];
  const int* rel_idx  = (const int*)d_in[15];

  // workspace layout (50,577,664 bytes total):
  //   [0]          dflag (int)
  //   [256]        winb  [T,96] bf16   8,429,568   (LN1 out, reused for LN2 out)
  //   [8,429,824]  xres  [T,96] bf16   8,429,568
  //   [16,859,392] slab            33,718,272 :
  //     attention phase: qkvb [T,288] bf16 (25,288,704) then attnb [T,96] bf16 (8,429,568)
  //     MLP phase:       h2 [T,384] bf16 (33,718,272) -- overwrites both (dead by then)
  char* ws = (char*)d_ws;
  int*  dflag = (int*)ws;
  u16*  winb  = (u16*)(ws + 256);
  u16*  xresb = (u16*)(ws + 256 + 8429568);
  u16*  qkvb  = (u16*)(ws + 256 + 2 * 8429568);
  u16*  attnb = (u16*)(ws + 256 + 2 * 8429568 + 25288704);
  u16*  h2b   = (u16*)(ws + 256 + 2 * 8429568);

  // 0. input dtype detection (fp32 vs bf16)
  detect_kernel<<<1, 64, 0, stream>>>((const u16*)x, dflag);
  // 1. LN1 + shift + window partition
  ln_gather_kernel<<<T_TOK / 4, 256, 0, stream>>>(x, g1, b1, winb, dflag);
  // 2. QKV GEMM -> qkvb [T,288]
  gemm_epi_kernel<0><<<dim3(T_TOK / 64, 288 / 32), 128, 0, stream>>>(
      winb, w_qkv, b_qkv, nullptr, nullptr, qkvb, 96, 288, dflag);
  // 3. fused attention -> attnb [T,96]
  attn_fused_kernel<<<dim3(22, 384), 256, 0, stream>>>(qkvb, bias_tb, maskm, rel_idx, attnb, dflag);
  // 4. proj GEMM + shortcut residual -> xres bf16 [T,96]
  gemm_epi_kernel<2><<<dim3(T_TOK / 64, 96 / 32), 128, 0, stream>>>(
      attnb, w_proj, b_proj, x, nullptr, xresb, 96, 96, dflag);
  // 5. LN2 -> winb
  ln2_kernel<<<T_TOK / 4, 256, 0, stream>>>(xresb, g2, b2, winb, dflag);
  // 6. FC1 + exact GELU -> h2 [T,384]
  gemm_epi_kernel<1><<<dim3(T_TOK / 64, 384 / 32), 128, 0, stream>>>(
      winb, w_fc1, b_fc1, nullptr, nullptr, h2b, 96, 384, dflag);
  // 7. FC2 + residual + scatter to spatial order -> d_out (fp32 if f32 else bf16)
  gemm_epi_kernel<3><<<dim3(T_TOK / 64, 96 / 32), 128, 0, stream>>>(
      h2b, w_fc2, b_fc2, nullptr, xresb, d_out, 384, 96, dflag);
}

// Round 5
// 462.350 us; speedup vs baseline: 6.5796x; 6.5796x over previous
//
#include <hip/hip_runtime.h>
#include <hip/hip_bf16.h>

typedef unsigned short u16;
typedef unsigned int u32;
typedef unsigned char u8;

#define T_TOK 43904   // 128 windows * 343 tokens
#define NTOK 343

typedef __attribute__((ext_vector_type(4))) float f32x4;
typedef __attribute__((ext_vector_type(8))) short s16x8;

__device__ __forceinline__ float bf2f(u32 v) { return __uint_as_float(v << 16); }
__device__ __forceinline__ u16 f2bf(float f) {
  u32 u = __float_as_uint(f);
  return (u16)((u + 0x7fffu + ((u >> 16) & 1u)) >> 16);
}

// ---- dual-dtype input loaders: f32!=0 -> data is fp32, else packed bf16 ----
__device__ __forceinline__ float ldf(const void* p, int f32, size_t i) {
  return f32 ? ((const float*)p)[i] : bf2f(((const u16*)p)[i]);
}
__device__ __forceinline__ float2 ld2(const void* p, int f32, size_t i) {  // i even
  if (f32) return *(const float2*)((const float*)p + i);
  u32 pk = *(const u32*)((const u16*)p + i);
  return make_float2(bf2f(pk & 0xffff), bf2f(pk >> 16));
}
__device__ __forceinline__ void ld8(const void* p, int f32, size_t i, float* o) {  // i%8==0
  if (f32) {
    float4 a = *(const float4*)((const float*)p + i);
    float4 b = *(const float4*)((const float*)p + i + 4);
    o[0] = a.x; o[1] = a.y; o[2] = a.z; o[3] = a.w;
    o[4] = b.x; o[5] = b.y; o[6] = b.z; o[7] = b.w;
  } else {
    uint4 pk = *(const uint4*)((const u16*)p + i);
    u32 v[4] = {pk.x, pk.y, pk.z, pk.w};
    #pragma unroll
    for (int q = 0; q < 4; q++) { o[2 * q] = bf2f(v[q] & 0xffff); o[2 * q + 1] = bf2f(v[q] >> 16); }
  }
}

// token index t (window-major) -> element offset of the (b,d,h,w) voxel in x/out
__device__ __forceinline__ size_t spatial_base(int t) {
  int win = t / 343, n = t - win * 343;
  int bb = win >> 6, wrem = win & 63;
  int wd = wrem >> 4, wh = (wrem >> 2) & 3, ww = wrem & 3;
  int td = n / 49; int r = n - td * 49; int th = r / 7; int tw = r - th * 7;
  int d0 = wd * 7 + td + 3; if (d0 >= 28) d0 -= 28;
  int h0 = wh * 7 + th + 3; if (h0 >= 28) h0 -= 28;
  int w0 = ww * 7 + tw + 3; if (w0 >= 28) w0 -= 28;
  return (size_t)(((bb * 28 + d0) * 28 + h0) * 28 + w0) * 96;
}

// shifted-window mask region id (exact reproduction of MONAI compute_mask)
__device__ __forceinline__ int zone3(int p) { return p < 21 ? 0 : (p < 25 ? 1 : 2); }
__device__ __forceinline__ int cid_of(int mw, int n) {
  int td = n / 49, rr = n - td * 49, th = rr / 7, tw = rr - th * 7;
  int d = (mw >> 4) * 7 + td, h = ((mw >> 2) & 3) * 7 + th, w = (mw & 3) * 7 + tw;
  return zone3(d) * 9 + zone3(h) * 3 + zone3(w);
}

// ---------------- dtype detector ----------------
__global__ __launch_bounds__(64) void detect_kernel(const u16* __restrict__ x, int* __restrict__ flag) {
  int lane = threadIdx.x;
  int bad = 0;
  #pragma unroll
  for (int q = 0; q < 8; q++) {
    u16 b = x[(lane * 8 + q) * 2];
    int e = (b >> 7) & 0xff;
    if (e >= 0x90) bad = 1;
  }
  unsigned long long m = __ballot(bad);
  if (lane == 0) *flag = (m != 0ull) ? 1 : 0;
}

// ---------------- LN1 + shift + window partition gather ----------------
__global__ __launch_bounds__(256) void ln_gather_kernel(
    const void* __restrict__ x, const void* __restrict__ g, const void* __restrict__ b,
    u16* __restrict__ outw, const int* __restrict__ dflag) {
  int f32 = __builtin_amdgcn_readfirstlane(dflag[0]);
  int t = blockIdx.x * 4 + (threadIdx.x >> 6);
  int lane = threadIdx.x & 63;
  size_t base = spatial_base(t);
  int c = lane * 2;
  float vx = 0.f, vy = 0.f;
  if (c < 96) { float2 p = ld2(x, f32, base + c); vx = p.x; vy = p.y; }
  float s = vx + vy, ss = vx * vx + vy * vy;
  #pragma unroll
  for (int o = 1; o < 64; o <<= 1) { s += __shfl_xor(s, o); ss += __shfl_xor(ss, o); }
  float mean = s * (1.f / 96.f);
  float var = ss * (1.f / 96.f) - mean * mean;
  float rstd = rsqrtf(var + 1e-5f);
  if (c < 96) {
    float2 gp = ld2(g, f32, c), bp = ld2(b, f32, c);
    float y0 = (vx - mean) * rstd * gp.x + bp.x;
    float y1 = (vy - mean) * rstd * gp.y + bp.y;
    *(u32*)(outw + (size_t)t * 96 + c) = (u32)f2bf(y0) | ((u32)f2bf(y1) << 16);
  }
}

// ---------------- LN2 (reads bf16 xres, token order) ----------------
__global__ __launch_bounds__(256) void ln2_kernel(
    const u16* __restrict__ xres, const void* __restrict__ g, const void* __restrict__ b,
    u16* __restrict__ outh, const int* __restrict__ dflag) {
  int f32 = __builtin_amdgcn_readfirstlane(dflag[0]);
  int t = blockIdx.x * 4 + (threadIdx.x >> 6);
  int lane = threadIdx.x & 63;
  int c = lane * 2;
  float vx = 0.f, vy = 0.f;
  if (c < 96) {
    u32 pk = *(const u32*)(xres + (size_t)t * 96 + c);
    vx = bf2f(pk & 0xffff); vy = bf2f(pk >> 16);
  }
  float s = vx + vy, ss = vx * vx + vy * vy;
  #pragma unroll
  for (int o = 1; o < 64; o <<= 1) { s += __shfl_xor(s, o); ss += __shfl_xor(ss, o); }
  float mean = s * (1.f / 96.f);
  float var = ss * (1.f / 96.f) - mean * mean;
  float rstd = rsqrtf(var + 1e-5f);
  if (c < 96) {
    float2 gp = ld2(g, f32, c), bp = ld2(b, f32, c);
    float y0 = (vx - mean) * rstd * gp.x + bp.x;
    float y1 = (vy - mean) * rstd * gp.y + bp.y;
    *(u32*)(outh + (size_t)t * 96 + c) = (u32)f2bf(y0) | ((u32)f2bf(y1) << 16);
  }
}

// ---------------- bias expand: B3[head][row][col(352)] = bias_table[rel[row][col]][head] ----------------
__global__ __launch_bounds__(256) void b3_kernel(
    const void* __restrict__ bias_table, const int* __restrict__ rel,
    u16* __restrict__ b3, const int* __restrict__ dflag) {
  int f32 = __builtin_amdgcn_readfirstlane(dflag[0]);
  int row = blockIdx.x, head = blockIdx.y;
  for (int c = threadIdx.x; c < 352; c += 256) {
    u16 v = 0;
    if (c < 343) v = f2bf(ldf(bias_table, f32, (size_t)rel[row * 343 + c] * 3 + head));
    b3[((size_t)head * 343 + row) * 352 + c] = v;
  }
}

// ---------------- tiled GEMM with fused epilogues ----------------
// out[m,n] = epi(sum_k A[m,k]*W[n,k] + bias[n]).  grid=(M/64, N/32), block=128.
// MODE 0: bf16 store           MODE 1: exact GELU -> bf16
// MODE 2: + x[spatial(m),n] -> bf16 xres
// MODE 3: + xres[m,n] -> store at spatial(m) in OUTPUT dtype (f32 ? fp32 : bf16)
// MODE 4: planar qkv store [sel*3+head][tok][32], q-plane scaled by 1/sqrt(32)
template <int MODE>
__global__ __launch_bounds__(128) void gemm_epi_kernel(
    const u16* __restrict__ A, const void* __restrict__ W, const void* __restrict__ bias,
    const void* __restrict__ xg, const u16* __restrict__ xres,
    void* __restrict__ outp, int K, int N, const int* __restrict__ dflag) {
  int f32 = __builtin_amdgcn_readfirstlane(dflag[0]);
  __shared__ float As[64][33];
  __shared__ float Ws[32][33];
  int tid = threadIdx.x;
  int m0 = blockIdx.x * 64, n0 = blockIdx.y * 32;
  int tm = (tid & 15) * 4, tn = (tid >> 4) * 4;
  float acc[4][4] = {};
  for (int k0 = 0; k0 < K; k0 += 32) {
    {
      int m = tid >> 1, kk = (tid & 1) * 16;
      const u32* src = (const u32*)(A + (size_t)(m0 + m) * K + k0 + kk);
      #pragma unroll
      for (int q = 0; q < 8; q++) {
        u32 pk = src[q];
        As[m][kk + 2 * q] = bf2f(pk & 0xffff);
        As[m][kk + 2 * q + 1] = bf2f(pk >> 16);
      }
    }
    {
      int n = tid >> 2, kk = (tid & 3) * 8;
      float f[8];
      ld8(W, f32, (size_t)(n0 + n) * K + k0 + kk, f);
      #pragma unroll
      for (int q = 0; q < 8; q++) Ws[n][kk + q] = f[q];
    }
    __syncthreads();
    #pragma unroll
    for (int kk = 0; kk < 32; kk++) {
      float a[4], w[4];
      #pragma unroll
      for (int i = 0; i < 4; i++) a[i] = As[tm + i][kk];
      #pragma unroll
      for (int j = 0; j < 4; j++) w[j] = Ws[tn + j][kk];
      #pragma unroll
      for (int i = 0; i < 4; i++)
        #pragma unroll
        for (int j = 0; j < 4; j++) acc[i][j] = fmaf(a[i], w[j], acc[i][j]);
    }
    __syncthreads();
  }
  #pragma unroll
  for (int i = 0; i < 4; i++) {
    int mm = m0 + tm + i;
    size_t sb = (MODE == 2 || MODE == 3) ? spatial_base(mm) : 0;
    #pragma unroll
    for (int j = 0; j < 4; j++) {
      int nn = n0 + tn + j;
      float v = acc[i][j] + ldf(bias, f32, nn);
      if (MODE == 1) v = 0.5f * v * (1.0f + erff(v * 0.70710678118f));
      if (MODE == 0 || MODE == 1) {
        ((u16*)outp)[(size_t)mm * N + nn] = f2bf(v);
      } else if (MODE == 2) {
        ((u16*)outp)[(size_t)mm * 96 + nn] = f2bf(v + ldf(xg, f32, sb + nn));
      } else if (MODE == 3) {
        float r = bf2f(xres[(size_t)mm * 96 + nn]) + v;
        if (f32) ((float*)outp)[sb + nn] = r;
        else     ((u16*)outp)[sb + nn] = f2bf(r);
      } else {  // MODE 4
        int sel = nn / 96, hd = (nn - sel * 96) >> 5, cc = nn & 31;
        float scl = (sel == 0) ? 0.17677669529663687f : 1.0f;
        ((u16*)outp)[((size_t)(sel * 3 + hd) * T_TOK + mm) * 32 + cc] = f2bf(v * scl);
      }
    }
  }
}

// ---------------- MFMA flash attention ----------------
// grid = (6, 384): blockIdx.y = wh = win*3+head, blockIdx.x = 64-row q-chunk.
// block = 256 (4 waves); wave w handles q-rows m0+w*16 .. +15.
// qkv planar: plane p = sel*3+head, addr = (p*T_TOK + win*343 + tok)*32 + c (bf16).
__global__ __launch_bounds__(256) void attn_mfma_kernel(
    const u16* __restrict__ qkv, const u16* __restrict__ b3,
    u16* __restrict__ attnb) {
  __shared__ u16 Ks[352 * 40];      // K[row][c], row stride 40
  __shared__ u16 Vt[32 * 360];      // V^T[c][tok], row stride 360
  __shared__ u16 Qs[4][16 * 40];    // per-wave Q tile
  __shared__ u16 Ps[4][16 * 40];    // per-wave P tile (C->A layout round-trip)
  __shared__ u8 cidk[352];

  int tid = threadIdx.x;
  int wh = blockIdx.y;
  int head = wh % 3;
  int win = wh / 3;
  int mw = win & 63;
  int m0 = blockIdx.x * 64;
  size_t wbase = (size_t)win * NTOK;

  const u16* qplane = qkv + ((size_t)(0 + head) * T_TOK + wbase) * 32;
  const u16* kplane = qkv + ((size_t)(3 + head) * T_TOK + wbase) * 32;
  const u16* vplane = qkv + ((size_t)(6 + head) * T_TOK + wbase) * 32;

  // ---- stage K (row-major, stride 40) and V (transposed, stride 360) ----
  for (int i = tid; i < 1372; i += 256) {       // 343*32/8 uint4s
    int tok = i >> 2, c = (i & 3) * 8;
    uint4 kv = *(const uint4*)(kplane + (size_t)tok * 32 + c);
    *(uint4*)&Ks[tok * 40 + c] = kv;
    uint4 vv = *(const uint4*)(vplane + (size_t)tok * 32 + c);
    u32 pv[4] = {vv.x, vv.y, vv.z, vv.w};
    #pragma unroll
    for (int q = 0; q < 4; q++) {
      Vt[(c + 2 * q) * 360 + tok] = (u16)(pv[q] & 0xffff);
      Vt[(c + 2 * q + 1) * 360 + tok] = (u16)(pv[q] >> 16);
    }
  }
  // zero K pad rows 343..351 (360 u16 = 180 u32)
  for (int i = tid; i < 180; i += 256) ((u32*)&Ks[343 * 40])[i] = 0;
  // zero Vt pad cols 343..359 (32 rows x 17)
  for (int i = tid; i < 544; i += 256) {
    int c = i / 17, t = 343 + (i - c * 17);
    Vt[c * 360 + t] = 0;
  }
  // region ids for mask
  for (int n = tid; n < 352; n += 256) cidk[n] = (n < 343) ? (u8)cid_of(mw, n) : (u8)255;
  // stage Q tiles (4 waves x 16 rows x 32 c = 256 uint4)
  {
    int wq = tid >> 6, r = (tid >> 2) & 15, c = (tid & 3) * 8;
    uint4 qv = *(const uint4*)(qplane + (size_t)(m0 + wq * 16 + r) * 32 + c);
    *(uint4*)&Qs[wq][r * 40 + c] = qv;
  }
  __syncthreads();

  int w = tid >> 6;
  int lane = tid & 63;
  int quad = lane >> 4;
  int l16 = lane & 15;
  int qbase = m0 + w * 16;

  s16x8 fq = *(const s16x8*)&Qs[w][l16 * 40 + quad * 8];

  // per-reg q-row region ids + B3 row pointers
  int cq[4];
  const u16* b3p[4];
  const u16* b3h = b3 + (size_t)head * 343 * 352;
  #pragma unroll
  for (int r = 0; r < 4; r++) {
    int qrow = qbase + quad * 4 + r;
    cq[r] = (qrow < NTOK) ? cid_of(mw, qrow) : 254;
    int qc = qrow < NTOK ? qrow : NTOK - 1;
    b3p[r] = b3h + (size_t)qc * 352;
  }

  float m_run[4], l_run[4];
  #pragma unroll
  for (int r = 0; r < 4; r++) { m_run[r] = -1e30f; l_run[r] = 0.f; }
  f32x4 o0 = {0.f, 0.f, 0.f, 0.f}, o1 = {0.f, 0.f, 0.f, 0.f};
  const f32x4 zz = {0.f, 0.f, 0.f, 0.f};

  for (int kt = 0; kt < 11; kt++) {
    int kb0 = kt * 32, kb1 = kt * 32 + 16;
    s16x8 fk0 = *(const s16x8*)&Ks[(kb0 + l16) * 40 + quad * 8];
    s16x8 fk1 = *(const s16x8*)&Ks[(kb1 + l16) * 40 + quad * 8];
    f32x4 s0 = __builtin_amdgcn_mfma_f32_16x16x32_bf16(fq, fk0, zz, 0, 0, 0);
    f32x4 s1 = __builtin_amdgcn_mfma_f32_16x16x32_bf16(fq, fk1, zz, 0, 0, 0);
    int ck0 = cidk[kb0 + l16], ck1 = cidk[kb1 + l16];
    #pragma unroll
    for (int r = 0; r < 4; r++) {
      float sv0 = s0[r] + bf2f(b3p[r][kb0 + l16]) + ((cq[r] == ck0) ? 0.f : -100.f);
      float sv1 = s1[r] + bf2f(b3p[r][kb1 + l16]) + ((cq[r] == ck1) ? 0.f : -100.f);
      float t = fmaxf(sv0, sv1);
      t = fmaxf(t, __shfl_xor(t, 1)); t = fmaxf(t, __shfl_xor(t, 2));
      t = fmaxf(t, __shfl_xor(t, 4)); t = fmaxf(t, __shfl_xor(t, 8));
      float mn = fmaxf(m_run[r], t);
      float al = __expf(m_run[r] - mn);
      m_run[r] = mn;
      float p0 = __expf(sv0 - mn), p1 = __expf(sv1 - mn);
      float ps = p0 + p1;
      ps += __shfl_xor(ps, 1); ps += __shfl_xor(ps, 2);
      ps += __shfl_xor(ps, 4); ps += __shfl_xor(ps, 8);
      l_run[r] = l_run[r] * al + ps;
      o0[r] *= al; o1[r] *= al;
      Ps[w][(quad * 4 + r) * 40 + l16] = f2bf(p0);
      Ps[w][(quad * 4 + r) * 40 + 16 + l16] = f2bf(p1);
    }
    __syncthreads();   // order Ps writes before A-layout reads (uniform trip count)
    s16x8 fp = *(const s16x8*)&Ps[w][l16 * 40 + quad * 8];
    s16x8 fv0 = *(const s16x8*)&Vt[l16 * 360 + kb0 + quad * 8];
    s16x8 fv1 = *(const s16x8*)&Vt[(16 + l16) * 360 + kb0 + quad * 8];
    o0 = __builtin_amdgcn_mfma_f32_16x16x32_bf16(fp, fv0, o0, 0, 0, 0);
    o1 = __builtin_amdgcn_mfma_f32_16x16x32_bf16(fp, fv1, o1, 0, 0, 0);
  }

  #pragma unroll
  for (int r = 0; r < 4; r++) {
    int qrow = qbase + quad * 4 + r;
    if (qrow < NTOK) {
      float rs = 1.0f / l_run[r];
      size_t ob = (wbase + qrow) * 96 + head * 32;
      attnb[ob + l16] = f2bf(o0[r] * rs);
      attnb[ob + 16 + l16] = f2bf(o1[r] * rs);
    }
  }
}

extern "C" void kernel_launch(void* const* d_in, const int* in_sizes, int n_in,
                              void* d_out, int out_size, void* d_ws, size_t ws_size,
                              hipStream_t stream) {
  (void)in_sizes; (void)n_in; (void)out_size; (void)ws_size;
  const void* x       = d_in[0];
  const void* g1      = d_in[2];
  const void* b1      = d_in[3];
  const void* w_qkv   = d_in[4];
  const void* b_qkv   = d_in[5];
  const void* bias_tb = d_in[6];
  const void* w_proj  = d_in[7];
  const void* b_proj  = d_in[8];
  const void* g2      = d_in[9];
  const void* b2      = d_in[10];
  const void* w_fc1   = d_in[11];
  const void* b_fc1   = d_in[12];
  const void* w_fc2   = d_in[13];
  const void* b_fc2   = d_in[14];
  const int* rel_idx  = (const int*)d_in[15];

  // workspace layout (~51.3 MB):
  //   [0]       dflag
  //   [256]     winb [T,96] bf16      8,429,568
  //   [+winb]   xres [T,96] bf16      8,429,568
  //   [+xres]   slab                 33,718,272 :
  //      attn phase: qkvb planar 9*T*32 bf16 (25,288,704) | attnb [T,96] (8,429,568)
  //      MLP phase:  h2 [T,384] bf16 (33,718,272)
  //   [+slab]   B3 [3][343][352] bf16   724,416
  char* ws = (char*)d_ws;
  int*  dflag = (int*)ws;
  u16*  winb  = (u16*)(ws + 256);
  u16*  xresb = (u16*)(ws + 256 + 8429568);
  u16*  qkvb  = (u16*)(ws + 256 + 2 * 8429568);
  u16*  attnb = (u16*)(ws + 256 + 2 * 8429568 + 25288704);
  u16*  h2b   = (u16*)(ws + 256 + 2 * 8429568);
  u16*  b3b   = (u16*)(ws + 256 + 2 * 8429568 + 33718272);

  // 0. input dtype detection (fp32 vs bf16)
  detect_kernel<<<1, 64, 0, stream>>>((const u16*)x, dflag);
  // 0b. bias table expansion
  b3_kernel<<<dim3(343, 3), 256, 0, stream>>>(bias_tb, rel_idx, b3b, dflag);
  // 1. LN1 + shift + window partition
  ln_gather_kernel<<<T_TOK / 4, 256, 0, stream>>>(x, g1, b1, winb, dflag);
  // 2. QKV GEMM -> planar qkv (q pre-scaled)
  gemm_epi_kernel<4><<<dim3(T_TOK / 64, 288 / 32), 128, 0, stream>>>(
      winb, w_qkv, b_qkv, nullptr, nullptr, qkvb, 96, 288, dflag);
  // 3. MFMA flash attention -> attnb [T,96]
  attn_mfma_kernel<<<dim3(6, 384), 256, 0, stream>>>(qkvb, b3b, attnb);
  // 4. proj GEMM + shortcut residual -> xres bf16 [T,96]
  gemm_epi_kernel<2><<<dim3(T_TOK / 64, 96 / 32), 128, 0, stream>>>(
      attnb, w_proj, b_proj, x, nullptr, xresb, 96, 96, dflag);
  // 5. LN2 -> winb
  ln2_kernel<<<T_TOK / 4, 256, 0, stream>>>(xresb, g2, b2, winb, dflag);
  // 6. FC1 + exact GELU -> h2 [T,384]
  gemm_epi_kernel<1><<<dim3(T_TOK / 64, 384 / 32), 128, 0, stream>>>(
      winb, w_fc1, b_fc1, nullptr, nullptr, h2b, 96, 384, dflag);
  // 7. FC2 + residual + scatter to spatial order -> d_out (fp32 if f32 else bf16)
  gemm_epi_kernel<3><<<dim3(T_TOK / 64, 96 / 32), 128, 0, stream>>>(
      h2b, w_fc2, b_fc2, nullptr, xresb, d_out, 384, 96, dflag);
}

// Round 6
// 333.435 us; speedup vs baseline: 9.1235x; 1.3866x over previous
//
#include <hip/hip_runtime.h>
#include <hip/hip_bf16.h>

typedef unsigned short u16;
typedef unsigned int u32;
typedef unsigned char u8;

#define T_TOK 43904   // 128 windows * 343 tokens
#define NTOK 343

typedef __attribute__((ext_vector_type(4))) float f32x4;
typedef __attribute__((ext_vector_type(8))) short s16x8;

__device__ __forceinline__ float bf2f(u32 v) { return __uint_as_float(v << 16); }
__device__ __forceinline__ u16 f2bf(float f) {
  u32 u = __float_as_uint(f);
  return (u16)((u + 0x7fffu + ((u >> 16) & 1u)) >> 16);
}

// ---- dual-dtype input loaders: f32!=0 -> data is fp32, else packed bf16 ----
__device__ __forceinline__ float ldf(const void* p, int f32, size_t i) {
  return f32 ? ((const float*)p)[i] : bf2f(((const u16*)p)[i]);
}
__device__ __forceinline__ float2 ld2(const void* p, int f32, size_t i) {  // i even
  if (f32) return *(const float2*)((const float*)p + i);
  u32 pk = *(const u32*)((const u16*)p + i);
  return make_float2(bf2f(pk & 0xffff), bf2f(pk >> 16));
}

// token index t (window-major) -> element offset of the (b,d,h,w) voxel in x/out
__device__ __forceinline__ size_t spatial_base(int t) {
  int win = t / 343, n = t - win * 343;
  int bb = win >> 6, wrem = win & 63;
  int wd = wrem >> 4, wh = (wrem >> 2) & 3, ww = wrem & 3;
  int td = n / 49; int r = n - td * 49; int th = r / 7; int tw = r - th * 7;
  int d0 = wd * 7 + td + 3; if (d0 >= 28) d0 -= 28;
  int h0 = wh * 7 + th + 3; if (h0 >= 28) h0 -= 28;
  int w0 = ww * 7 + tw + 3; if (w0 >= 28) w0 -= 28;
  return (size_t)(((bb * 28 + d0) * 28 + h0) * 28 + w0) * 96;
}

// shifted-window mask region id (exact reproduction of MONAI compute_mask)
__device__ __forceinline__ int zone3(int p) { return p < 21 ? 0 : (p < 25 ? 1 : 2); }
__device__ __forceinline__ int cid_of(int mw, int n) {
  int td = n / 49, rr = n - td * 49, th = rr / 7, tw = rr - th * 7;
  int d = (mw >> 4) * 7 + td, h = ((mw >> 2) & 3) * 7 + th, w = (mw & 3) * 7 + tw;
  return zone3(d) * 9 + zone3(h) * 3 + zone3(w);
}

// ---------------- dtype detector ----------------
__global__ __launch_bounds__(64) void detect_kernel(const u16* __restrict__ x, int* __restrict__ flag) {
  int lane = threadIdx.x;
  int bad = 0;
  #pragma unroll
  for (int q = 0; q < 8; q++) {
    u16 b = x[(lane * 8 + q) * 2];
    int e = (b >> 7) & 0xff;
    if (e >= 0x90) bad = 1;
  }
  unsigned long long m = __ballot(bad);
  if (lane == 0) *flag = (m != 0ull) ? 1 : 0;
}

// ---------------- weight conversion -> bf16 [n][k] concat ----------------
// segments: w_qkv 27648 | w_proj 9216 | w_fc1 36864 | w_fc2 36864  (110592 total)
__global__ __launch_bounds__(256) void wconv_kernel(
    const void* __restrict__ w0, const void* __restrict__ w1,
    const void* __restrict__ w2, const void* __restrict__ w3,
    u16* __restrict__ out, const int* __restrict__ dflag) {
  int f32 = __builtin_amdgcn_readfirstlane(dflag[0]);
  int g = blockIdx.x * 256 + threadIdx.x;
  if (g >= 110592) return;
  float v;
  if (g < 27648)      v = ldf(w0, f32, g);
  else if (g < 36864) v = ldf(w1, f32, g - 27648);
  else if (g < 73728) v = ldf(w2, f32, g - 36864);
  else                v = ldf(w3, f32, g - 73728);
  out[g] = f2bf(v);
}

// ---------------- LN1 + shift + window partition gather ----------------
__global__ __launch_bounds__(256) void ln_gather_kernel(
    const void* __restrict__ x, const void* __restrict__ g, const void* __restrict__ b,
    u16* __restrict__ outw, const int* __restrict__ dflag) {
  int f32 = __builtin_amdgcn_readfirstlane(dflag[0]);
  int t = blockIdx.x * 4 + (threadIdx.x >> 6);
  int lane = threadIdx.x & 63;
  size_t base = spatial_base(t);
  int c = lane * 2;
  float vx = 0.f, vy = 0.f;
  if (c < 96) { float2 p = ld2(x, f32, base + c); vx = p.x; vy = p.y; }
  float s = vx + vy, ss = vx * vx + vy * vy;
  #pragma unroll
  for (int o = 1; o < 64; o <<= 1) { s += __shfl_xor(s, o); ss += __shfl_xor(ss, o); }
  float mean = s * (1.f / 96.f);
  float var = ss * (1.f / 96.f) - mean * mean;
  float rstd = rsqrtf(var + 1e-5f);
  if (c < 96) {
    float2 gp = ld2(g, f32, c), bp = ld2(b, f32, c);
    float y0 = (vx - mean) * rstd * gp.x + bp.x;
    float y1 = (vy - mean) * rstd * gp.y + bp.y;
    *(u32*)(outw + (size_t)t * 96 + c) = (u32)f2bf(y0) | ((u32)f2bf(y1) << 16);
  }
}

// ---------------- LN2 (reads bf16 xres, token order) ----------------
__global__ __launch_bounds__(256) void ln2_kernel(
    const u16* __restrict__ xres, const void* __restrict__ g, const void* __restrict__ b,
    u16* __restrict__ outh, const int* __restrict__ dflag) {
  int f32 = __builtin_amdgcn_readfirstlane(dflag[0]);
  int t = blockIdx.x * 4 + (threadIdx.x >> 6);
  int lane = threadIdx.x & 63;
  int c = lane * 2;
  float vx = 0.f, vy = 0.f;
  if (c < 96) {
    u32 pk = *(const u32*)(xres + (size_t)t * 96 + c);
    vx = bf2f(pk & 0xffff); vy = bf2f(pk >> 16);
  }
  float s = vx + vy, ss = vx * vx + vy * vy;
  #pragma unroll
  for (int o = 1; o < 64; o <<= 1) { s += __shfl_xor(s, o); ss += __shfl_xor(ss, o); }
  float mean = s * (1.f / 96.f);
  float var = ss * (1.f / 96.f) - mean * mean;
  float rstd = rsqrtf(var + 1e-5f);
  if (c < 96) {
    float2 gp = ld2(g, f32, c), bp = ld2(b, f32, c);
    float y0 = (vx - mean) * rstd * gp.x + bp.x;
    float y1 = (vy - mean) * rstd * gp.y + bp.y;
    *(u32*)(outh + (size_t)t * 96 + c) = (u32)f2bf(y0) | ((u32)f2bf(y1) << 16);
  }
}

// ---------------- bias expand: B3[head][row][col(352)] = bias_table[rel[row][col]][head] ----------------
__global__ __launch_bounds__(256) void b3_kernel(
    const void* __restrict__ bias_table, const int* __restrict__ rel,
    u16* __restrict__ b3, const int* __restrict__ dflag) {
  int f32 = __builtin_amdgcn_readfirstlane(dflag[0]);
  int row = blockIdx.x, head = blockIdx.y;
  for (int c = threadIdx.x; c < 352; c += 256) {
    u16 v = 0;
    if (c < 343) v = f2bf(ldf(bias_table, f32, (size_t)rel[row * 343 + c] * 3 + head));
    b3[((size_t)head * 343 + row) * 352 + c] = v;
  }
}

// ---------------- MFMA GEMM with fused epilogues ----------------
// out[m,n] = epi(sum_k A[m,k]*Wb[n,k] + bias[n]).  A,Wb bf16.
// grid = (M/128, N/96), block = 256 (4 waves). Wave w: rows w*32..+31, all 96 cols.
// MODE 1: exact GELU -> bf16 [m][N]
// MODE 2: + x[spatial(m),n] -> bf16 xres [m][96]
// MODE 3: + xres[m,n] -> store at spatial(m) in OUTPUT dtype (f32 ? fp32 : bf16)
// MODE 4: planar qkv store [sel*3+head][tok][32], q-plane scaled by 1/sqrt(32)
template <int MODE>
__global__ __launch_bounds__(256) void gemm_mfma_kernel(
    const u16* __restrict__ A, const u16* __restrict__ Wb, const void* __restrict__ bias,
    const void* __restrict__ xg, const u16* __restrict__ xres,
    void* __restrict__ outp, int K, int N, const int* __restrict__ dflag) {
  int f32 = __builtin_amdgcn_readfirstlane(dflag[0]);
  __shared__ u16 As[128 * 40];   // row stride 40 (80 B, 16B-aligned; worst 2-way alias = free)
  __shared__ u16 Ws[96 * 40];
  int tid = threadIdx.x;
  int m0 = blockIdx.x * 128, n0 = blockIdx.y * 96;
  int w = tid >> 6, lane = tid & 63, quad = lane >> 4, l16 = lane & 15;
  f32x4 acc[2][6];
  #pragma unroll
  for (int i = 0; i < 2; i++)
    #pragma unroll
    for (int j = 0; j < 6; j++) acc[i][j] = (f32x4){0.f, 0.f, 0.f, 0.f};

  for (int k0 = 0; k0 < K; k0 += 32) {
    #pragma unroll
    for (int i = tid; i < 512; i += 256) {   // A: 128 rows x 32 k
      int row = i >> 2, c = (i & 3) * 8;
      *(uint4*)&As[row * 40 + c] = *(const uint4*)(A + (size_t)(m0 + row) * K + k0 + c);
    }
    for (int i = tid; i < 384; i += 256) {   // W: 96 rows x 32 k
      int row = i >> 2, c = (i & 3) * 8;
      *(uint4*)&Ws[row * 40 + c] = *(const uint4*)(Wb + (size_t)(n0 + row) * K + k0 + c);
    }
    __syncthreads();
    s16x8 fa0 = *(const s16x8*)&As[(w * 32 + l16) * 40 + quad * 8];
    s16x8 fa1 = *(const s16x8*)&As[(w * 32 + 16 + l16) * 40 + quad * 8];
    #pragma unroll
    for (int j = 0; j < 6; j++) {
      s16x8 fb = *(const s16x8*)&Ws[(j * 16 + l16) * 40 + quad * 8];
      acc[0][j] = __builtin_amdgcn_mfma_f32_16x16x32_bf16(fa0, fb, acc[0][j], 0, 0, 0);
      acc[1][j] = __builtin_amdgcn_mfma_f32_16x16x32_bf16(fa1, fb, acc[1][j], 0, 0, 0);
    }
    __syncthreads();
  }
  // epilogue: D row = quad*4+r (+16i), col = l16 (+16j)
  #pragma unroll
  for (int i = 0; i < 2; i++) {
    #pragma unroll
    for (int r = 0; r < 4; r++) {
      int mm = m0 + w * 32 + i * 16 + quad * 4 + r;
      size_t sb = (MODE == 2 || MODE == 3) ? spatial_base(mm) : 0;
      #pragma unroll
      for (int j = 0; j < 6; j++) {
        int nn = n0 + j * 16 + l16;
        float v = acc[i][j][r] + ldf(bias, f32, nn);
        if (MODE == 1) {
          v = 0.5f * v * (1.0f + erff(v * 0.70710678118f));
          ((u16*)outp)[(size_t)mm * N + nn] = f2bf(v);
        } else if (MODE == 2) {
          ((u16*)outp)[(size_t)mm * 96 + nn] = f2bf(v + ldf(xg, f32, sb + nn));
        } else if (MODE == 3) {
          float rr = bf2f(xres[(size_t)mm * 96 + nn]) + v;
          if (f32) ((float*)outp)[sb + nn] = rr;
          else     ((u16*)outp)[sb + nn] = f2bf(rr);
        } else {  // MODE 4
          int sel = nn / 96, hd = (nn - sel * 96) >> 5, cc = nn & 31;
          float scl = (sel == 0) ? 0.17677669529663687f : 1.0f;
          ((u16*)outp)[((size_t)(sel * 3 + hd) * T_TOK + mm) * 32 + cc] = f2bf(v * scl);
        }
      }
    }
  }
}

// ---------------- MFMA flash attention ----------------
// grid = (6, 384): blockIdx.y = wh = win*3+head, blockIdx.x = 64-row q-chunk.
__global__ __launch_bounds__(256) void attn_mfma_kernel(
    const u16* __restrict__ qkv, const u16* __restrict__ b3,
    u16* __restrict__ attnb) {
  __shared__ u16 Ks[352 * 40];      // K[row][c], row stride 40
  __shared__ u16 Vt[32 * 360];      // V^T[c][tok], row stride 360
  __shared__ u16 Qs[4][16 * 40];    // per-wave Q tile
  __shared__ u16 Ps[4][16 * 40];    // per-wave P tile (C->A layout round-trip)
  __shared__ u8 cidk[352];

  int tid = threadIdx.x;
  int wh = blockIdx.y;
  int head = wh % 3;
  int win = wh / 3;
  int mw = win & 63;
  int m0 = blockIdx.x * 64;
  size_t wbase = (size_t)win * NTOK;

  const u16* qplane = qkv + ((size_t)(0 + head) * T_TOK + wbase) * 32;
  const u16* kplane = qkv + ((size_t)(3 + head) * T_TOK + wbase) * 32;
  const u16* vplane = qkv + ((size_t)(6 + head) * T_TOK + wbase) * 32;

  for (int i = tid; i < 1372; i += 256) {       // 343*32/8 uint4s
    int tok = i >> 2, c = (i & 3) * 8;
    uint4 kv = *(const uint4*)(kplane + (size_t)tok * 32 + c);
    *(uint4*)&Ks[tok * 40 + c] = kv;
    uint4 vv = *(const uint4*)(vplane + (size_t)tok * 32 + c);
    u32 pv[4] = {vv.x, vv.y, vv.z, vv.w};
    #pragma unroll
    for (int q = 0; q < 4; q++) {
      Vt[(c + 2 * q) * 360 + tok] = (u16)(pv[q] & 0xffff);
      Vt[(c + 2 * q + 1) * 360 + tok] = (u16)(pv[q] >> 16);
    }
  }
  for (int i = tid; i < 180; i += 256) ((u32*)&Ks[343 * 40])[i] = 0;
  for (int i = tid; i < 544; i += 256) {
    int c = i / 17, t = 343 + (i - c * 17);
    Vt[c * 360 + t] = 0;
  }
  for (int n = tid; n < 352; n += 256) cidk[n] = (n < 343) ? (u8)cid_of(mw, n) : (u8)255;
  {
    int wq = tid >> 6, r = (tid >> 2) & 15, c = (tid & 3) * 8;
    uint4 qv = *(const uint4*)(qplane + (size_t)(m0 + wq * 16 + r) * 32 + c);
    *(uint4*)&Qs[wq][r * 40 + c] = qv;
  }
  __syncthreads();

  int w = tid >> 6;
  int lane = tid & 63;
  int quad = lane >> 4;
  int l16 = lane & 15;
  int qbase = m0 + w * 16;

  s16x8 fq = *(const s16x8*)&Qs[w][l16 * 40 + quad * 8];

  int cq[4];
  const u16* b3p[4];
  const u16* b3h = b3 + (size_t)head * 343 * 352;
  #pragma unroll
  for (int r = 0; r < 4; r++) {
    int qrow = qbase + quad * 4 + r;
    cq[r] = (qrow < NTOK) ? cid_of(mw, qrow) : 254;
    int qc = qrow < NTOK ? qrow : NTOK - 1;
    b3p[r] = b3h + (size_t)qc * 352;
  }

  float m_run[4], l_run[4];
  #pragma unroll
  for (int r = 0; r < 4; r++) { m_run[r] = -1e30f; l_run[r] = 0.f; }
  f32x4 o0 = {0.f, 0.f, 0.f, 0.f}, o1 = {0.f, 0.f, 0.f, 0.f};
  const f32x4 zz = {0.f, 0.f, 0.f, 0.f};

  for (int kt = 0; kt < 11; kt++) {
    int kb0 = kt * 32, kb1 = kt * 32 + 16;
    s16x8 fk0 = *(const s16x8*)&Ks[(kb0 + l16) * 40 + quad * 8];
    s16x8 fk1 = *(const s16x8*)&Ks[(kb1 + l16) * 40 + quad * 8];
    f32x4 s0 = __builtin_amdgcn_mfma_f32_16x16x32_bf16(fq, fk0, zz, 0, 0, 0);
    f32x4 s1 = __builtin_amdgcn_mfma_f32_16x16x32_bf16(fq, fk1, zz, 0, 0, 0);
    int ck0 = cidk[kb0 + l16], ck1 = cidk[kb1 + l16];
    #pragma unroll
    for (int r = 0; r < 4; r++) {
      float sv0 = s0[r] + bf2f(b3p[r][kb0 + l16]) + ((cq[r] == ck0) ? 0.f : -100.f);
      float sv1 = s1[r] + bf2f(b3p[r][kb1 + l16]) + ((cq[r] == ck1) ? 0.f : -100.f);
      float t = fmaxf(sv0, sv1);
      t = fmaxf(t, __shfl_xor(t, 1)); t = fmaxf(t, __shfl_xor(t, 2));
      t = fmaxf(t, __shfl_xor(t, 4)); t = fmaxf(t, __shfl_xor(t, 8));
      float mn = fmaxf(m_run[r], t);
      float al = __expf(m_run[r] - mn);
      m_run[r] = mn;
      float p0 = __expf(sv0 - mn), p1 = __expf(sv1 - mn);
      float ps = p0 + p1;
      ps += __shfl_xor(ps, 1); ps += __shfl_xor(ps, 2);
      ps += __shfl_xor(ps, 4); ps += __shfl_xor(ps, 8);
      l_run[r] = l_run[r] * al + ps;
      o0[r] *= al; o1[r] *= al;
      Ps[w][(quad * 4 + r) * 40 + l16] = f2bf(p0);
      Ps[w][(quad * 4 + r) * 40 + 16 + l16] = f2bf(p1);
    }
    __syncthreads();   // order Ps writes before A-layout reads (uniform trip count)
    s16x8 fp = *(const s16x8*)&Ps[w][l16 * 40 + quad * 8];
    s16x8 fv0 = *(const s16x8*)&Vt[l16 * 360 + kb0 + quad * 8];
    s16x8 fv1 = *(const s16x8*)&Vt[(16 + l16) * 360 + kb0 + quad * 8];
    o0 = __builtin_amdgcn_mfma_f32_16x16x32_bf16(fp, fv0, o0, 0, 0, 0);
    o1 = __builtin_amdgcn_mfma_f32_16x16x32_bf16(fp, fv1, o1, 0, 0, 0);
  }

  #pragma unroll
  for (int r = 0; r < 4; r++) {
    int qrow = qbase + quad * 4 + r;
    if (qrow < NTOK) {
      float rs = 1.0f / l_run[r];
      size_t ob = (wbase + qrow) * 96 + head * 32;
      attnb[ob + l16] = f2bf(o0[r] * rs);
      attnb[ob + 16 + l16] = f2bf(o1[r] * rs);
    }
  }
}

extern "C" void kernel_launch(void* const* d_in, const int* in_sizes, int n_in,
                              void* d_out, int out_size, void* d_ws, size_t ws_size,
                              hipStream_t stream) {
  (void)in_sizes; (void)n_in; (void)out_size; (void)ws_size;
  const void* x       = d_in[0];
  const void* g1      = d_in[2];
  const void* b1      = d_in[3];
  const void* w_qkv   = d_in[4];
  const void* b_qkv   = d_in[5];
  const void* bias_tb = d_in[6];
  const void* w_proj  = d_in[7];
  const void* b_proj  = d_in[8];
  const void* g2      = d_in[9];
  const void* b2      = d_in[10];
  const void* w_fc1   = d_in[11];
  const void* b_fc1   = d_in[12];
  const void* w_fc2   = d_in[13];
  const void* b_fc2   = d_in[14];
  const int* rel_idx  = (const int*)d_in[15];

  // workspace layout (~51.6 MB):
  //   [0]          dflag
  //   [256]        winb [T,96] bf16      8,429,568
  //   [8,429,824]  xres [T,96] bf16      8,429,568
  //   [16,859,392] slab                 33,718,272 :
  //      attn phase: qkvb planar 9*T*32 bf16 (25,288,704) | attnb [T,96] (8,429,568)
  //      MLP phase:  h2 [T,384] bf16 (33,718,272)
  //   [50,577,664] B3 [3][343][352] bf16   724,416
  //   [51,302,080] wcat bf16              221,184
  char* ws = (char*)d_ws;
  int*  dflag = (int*)ws;
  u16*  winb  = (u16*)(ws + 256);
  u16*  xresb = (u16*)(ws + 256 + 8429568);
  u16*  qkvb  = (u16*)(ws + 256 + 2 * 8429568);
  u16*  attnb = (u16*)(ws + 256 + 2 * 8429568 + 25288704);
  u16*  h2b   = (u16*)(ws + 256 + 2 * 8429568);
  u16*  b3b   = (u16*)(ws + 256 + 2 * 8429568 + 33718272);
  u16*  wcat  = (u16*)(ws + 256 + 2 * 8429568 + 33718272 + 724416);
  u16*  w_qkvb = wcat;
  u16*  w_projb = wcat + 27648;
  u16*  w_fc1b = wcat + 36864;
  u16*  w_fc2b = wcat + 73728;

  // 0. input dtype detection (fp32 vs bf16) + weight conversion + bias expansion
  detect_kernel<<<1, 64, 0, stream>>>((const u16*)x, dflag);
  wconv_kernel<<<432, 256, 0, stream>>>(w_qkv, w_proj, w_fc1, w_fc2, wcat, dflag);
  b3_kernel<<<dim3(343, 3), 256, 0, stream>>>(bias_tb, rel_idx, b3b, dflag);
  // 1. LN1 + shift + window partition
  ln_gather_kernel<<<T_TOK / 4, 256, 0, stream>>>(x, g1, b1, winb, dflag);
  // 2. QKV GEMM -> planar qkv (q pre-scaled)
  gemm_mfma_kernel<4><<<dim3(T_TOK / 128, 3), 256, 0, stream>>>(
      winb, w_qkvb, b_qkv, nullptr, nullptr, qkvb, 96, 288, dflag);
  // 3. MFMA flash attention -> attnb [T,96]
  attn_mfma_kernel<<<dim3(6, 384), 256, 0, stream>>>(qkvb, b3b, attnb);
  // 4. proj GEMM + shortcut residual -> xres bf16 [T,96]
  gemm_mfma_kernel<2><<<dim3(T_TOK / 128, 1), 256, 0, stream>>>(
      attnb, w_projb, b_proj, x, nullptr, xresb, 96, 96, dflag);
  // 5. LN2 -> winb
  ln2_kernel<<<T_TOK / 4, 256, 0, stream>>>(xresb, g2, b2, winb, dflag);
  // 6. FC1 + exact GELU -> h2 [T,384]
  gemm_mfma_kernel<1><<<dim3(T_TOK / 128, 4), 256, 0, stream>>>(
      winb, w_fc1b, b_fc1, nullptr, nullptr, h2b, 96, 384, dflag);
  // 7. FC2 + residual + scatter to spatial order -> d_out (fp32 if f32 else bf16)
  gemm_mfma_kernel<3><<<dim3(T_TOK / 128, 1), 256, 0, stream>>>(
      h2b, w_fc2b, b_fc2, nullptr, xresb, d_out, 384, 96, dflag);
}

// Round 7
// 258.460 us; speedup vs baseline: 11.7701x; 1.2901x over previous
//
#include <hip/hip_runtime.h>
#include <hip/hip_bf16.h>

typedef unsigned short u16;
typedef unsigned int u32;
typedef unsigned char u8;

#define T_TOK 43904   // 128 windows * 343 tokens
#define NTOK 343

typedef __attribute__((ext_vector_type(4))) float f32x4;
typedef __attribute__((ext_vector_type(8))) short s16x8;

__device__ __forceinline__ float bf2f(u32 v) { return __uint_as_float(v << 16); }
__device__ __forceinline__ u16 f2bf(float f) {
  u32 u = __float_as_uint(f);
  return (u16)((u + 0x7fffu + ((u >> 16) & 1u)) >> 16);
}

// ---- dual-dtype input loaders: f32!=0 -> data is fp32, else packed bf16 ----
__device__ __forceinline__ float ldf(const void* p, int f32, size_t i) {
  return f32 ? ((const float*)p)[i] : bf2f(((const u16*)p)[i]);
}
__device__ __forceinline__ float2 ld2(const void* p, int f32, size_t i) {  // i even
  if (f32) return *(const float2*)((const float*)p + i);
  u32 pk = *(const u32*)((const u16*)p + i);
  return make_float2(bf2f(pk & 0xffff), bf2f(pk >> 16));
}

// token index t (window-major) -> element offset of the (b,d,h,w) voxel in x/out
__device__ __forceinline__ size_t spatial_base(int t) {
  int win = t / 343, n = t - win * 343;
  int bb = win >> 6, wrem = win & 63;
  int wd = wrem >> 4, wh = (wrem >> 2) & 3, ww = wrem & 3;
  int td = n / 49; int r = n - td * 49; int th = r / 7; int tw = r - th * 7;
  int d0 = wd * 7 + td + 3; if (d0 >= 28) d0 -= 28;
  int h0 = wh * 7 + th + 3; if (h0 >= 28) h0 -= 28;
  int w0 = ww * 7 + tw + 3; if (w0 >= 28) w0 -= 28;
  return (size_t)(((bb * 28 + d0) * 28 + h0) * 28 + w0) * 96;
}

// shifted-window mask region id (exact reproduction of MONAI compute_mask)
__device__ __forceinline__ int zone3(int p) { return p < 21 ? 0 : (p < 25 ? 1 : 2); }
__device__ __forceinline__ int cid_of(int mw, int n) {
  int td = n / 49, rr = n - td * 49, th = rr / 7, tw = rr - th * 7;
  int d = (mw >> 4) * 7 + td, h = ((mw >> 2) & 3) * 7 + th, w = (mw & 3) * 7 + tw;
  return zone3(d) * 9 + zone3(h) * 3 + zone3(w);
}

// ---------------- dtype detector ----------------
__global__ __launch_bounds__(64) void detect_kernel(const u16* __restrict__ x, int* __restrict__ flag) {
  int lane = threadIdx.x;
  int bad = 0;
  #pragma unroll
  for (int q = 0; q < 8; q++) {
    u16 b = x[(lane * 8 + q) * 2];
    int e = (b >> 7) & 0xff;
    if (e >= 0x90) bad = 1;
  }
  unsigned long long m = __ballot(bad);
  if (lane == 0) *flag = (m != 0ull) ? 1 : 0;
}

// ---------------- weight conversion -> bf16 [n][k] concat ----------------
__global__ __launch_bounds__(256) void wconv_kernel(
    const void* __restrict__ w0, const void* __restrict__ w1,
    const void* __restrict__ w2, const void* __restrict__ w3,
    u16* __restrict__ out, const int* __restrict__ dflag) {
  int f32 = __builtin_amdgcn_readfirstlane(dflag[0]);
  int g = blockIdx.x * 256 + threadIdx.x;
  if (g >= 110592) return;
  float v;
  if (g < 27648)      v = ldf(w0, f32, g);
  else if (g < 36864) v = ldf(w1, f32, g - 27648);
  else if (g < 73728) v = ldf(w2, f32, g - 36864);
  else                v = ldf(w3, f32, g - 73728);
  out[g] = f2bf(v);
}

// ---------------- LN1 + shift + window partition gather ----------------
__global__ __launch_bounds__(256) void ln_gather_kernel(
    const void* __restrict__ x, const void* __restrict__ g, const void* __restrict__ b,
    u16* __restrict__ outw, const int* __restrict__ dflag) {
  int f32 = __builtin_amdgcn_readfirstlane(dflag[0]);
  int t = blockIdx.x * 4 + (threadIdx.x >> 6);
  int lane = threadIdx.x & 63;
  size_t base = spatial_base(t);
  int c = lane * 2;
  float vx = 0.f, vy = 0.f;
  if (c < 96) { float2 p = ld2(x, f32, base + c); vx = p.x; vy = p.y; }
  float s = vx + vy, ss = vx * vx + vy * vy;
  #pragma unroll
  for (int o = 1; o < 64; o <<= 1) { s += __shfl_xor(s, o); ss += __shfl_xor(ss, o); }
  float mean = s * (1.f / 96.f);
  float var = ss * (1.f / 96.f) - mean * mean;
  float rstd = rsqrtf(var + 1e-5f);
  if (c < 96) {
    float2 gp = ld2(g, f32, c), bp = ld2(b, f32, c);
    float y0 = (vx - mean) * rstd * gp.x + bp.x;
    float y1 = (vy - mean) * rstd * gp.y + bp.y;
    *(u32*)(outw + (size_t)t * 96 + c) = (u32)f2bf(y0) | ((u32)f2bf(y1) << 16);
  }
}

// ---------------- bias expand: B3[head][row][col(352)] ----------------
__global__ __launch_bounds__(256) void b3_kernel(
    const void* __restrict__ bias_table, const int* __restrict__ rel,
    u16* __restrict__ b3, const int* __restrict__ dflag) {
  int f32 = __builtin_amdgcn_readfirstlane(dflag[0]);
  int row = blockIdx.x, head = blockIdx.y;
  for (int c = threadIdx.x; c < 352; c += 256) {
    u16 v = 0;
    if (c < 343) v = f2bf(ldf(bias_table, f32, (size_t)rel[row * 343 + c] * 3 + head));
    b3[((size_t)head * 343 + row) * 352 + c] = v;
  }
}

// ---------------- MFMA GEMM, full-K=96 staging, fused epilogues ----------------
// out[m,n] = epi(sum_k A[m,k]*Wb[n,k] + bias[n]).  grid=(343, N/96), block=256.
// MODE 1: exact GELU -> bf16 [m][N]
// MODE 2: + x[spatial(m),n] -> bf16 xres (outp) AND LN2 -> bf16 winb (out2)
// MODE 3: + xres_in[m,n] -> store at spatial(m) in OUTPUT dtype (f32 ? fp32 : bf16)
// MODE 4: planar qkv store [sel*3+head][tok][32], q-plane scaled by 1/sqrt(32)
template <int MODE>
__global__ __launch_bounds__(256) void gemm_mfma_kernel(
    const u16* __restrict__ A, const u16* __restrict__ Wb, const void* __restrict__ bias,
    const void* __restrict__ xg, const u16* __restrict__ xres_in,
    const void* __restrict__ gg, const void* __restrict__ bb,
    u16* __restrict__ out2, void* __restrict__ outp,
    int K, int N, const int* __restrict__ dflag) {
  int f32 = __builtin_amdgcn_readfirstlane(dflag[0]);
  __shared__ alignas(16) u16 As[128 * 104];   // stride 104: 16B-aligned rows, 2-way banks (free)
  __shared__ alignas(16) u16 Ws[96 * 104];
  int tid = threadIdx.x;
  int m0 = blockIdx.x * 128, n0 = blockIdx.y * 96;
  int w = tid >> 6, lane = tid & 63, quad = lane >> 4, l16 = lane & 15;
  f32x4 acc[2][6];
  #pragma unroll
  for (int i = 0; i < 2; i++)
    #pragma unroll
    for (int j = 0; j < 6; j++) acc[i][j] = (f32x4){0.f, 0.f, 0.f, 0.f};

  for (int kb = 0; kb < K; kb += 96) {
    if (kb) __syncthreads();
    for (int i = tid; i < 1536; i += 256) {   // A: 128 rows x 96 k (12 uint4/row)
      int row = i / 12; int c = (i - row * 12) * 8;
      *(uint4*)&As[row * 104 + c] = *(const uint4*)(A + (size_t)(m0 + row) * K + kb + c);
    }
    for (int i = tid; i < 1152; i += 256) {   // W: 96 rows x 96 k
      int row = i / 12; int c = (i - row * 12) * 8;
      *(uint4*)&Ws[row * 104 + c] = *(const uint4*)(Wb + (size_t)(n0 + row) * K + kb + c);
    }
    __syncthreads();
    #pragma unroll
    for (int kc = 0; kc < 3; kc++) {
      s16x8 fa0 = *(const s16x8*)&As[(w * 32 + l16) * 104 + kc * 32 + quad * 8];
      s16x8 fa1 = *(const s16x8*)&As[(w * 32 + 16 + l16) * 104 + kc * 32 + quad * 8];
      #pragma unroll
      for (int j = 0; j < 6; j++) {
        s16x8 fb = *(const s16x8*)&Ws[(j * 16 + l16) * 104 + kc * 32 + quad * 8];
        acc[0][j] = __builtin_amdgcn_mfma_f32_16x16x32_bf16(fa0, fb, acc[0][j], 0, 0, 0);
        acc[1][j] = __builtin_amdgcn_mfma_f32_16x16x32_bf16(fa1, fb, acc[1][j], 0, 0, 0);
      }
    }
  }
  // per-column constants
  float bv[6], gv[6], b2v[6];
  #pragma unroll
  for (int j = 0; j < 6; j++) {
    int nn = n0 + j * 16 + l16;
    bv[j] = ldf(bias, f32, nn);
    if (MODE == 2) { gv[j] = ldf(gg, f32, nn); b2v[j] = ldf(bb, f32, nn); }
  }
  #pragma unroll
  for (int i = 0; i < 2; i++) {
    #pragma unroll
    for (int r = 0; r < 4; r++) {
      int mm = m0 + w * 32 + i * 16 + quad * 4 + r;
      size_t sb = (MODE == 2 || MODE == 3) ? spatial_base(mm) : 0;
      if (MODE == 2) {
        // residual add + store xres; then LN over the row (fp32)
        float rv[6];
        float s = 0.f, ss = 0.f;
        #pragma unroll
        for (int j = 0; j < 6; j++) {
          int nn = j * 16 + l16;
          float v = acc[i][j][r] + bv[j] + ldf(xg, f32, sb + nn);
          rv[j] = v; s += v; ss += v * v;
          ((u16*)outp)[(size_t)mm * 96 + nn] = f2bf(v);
        }
        #pragma unroll
        for (int o = 1; o < 16; o <<= 1) { s += __shfl_xor(s, o); ss += __shfl_xor(ss, o); }
        float mean = s * (1.f / 96.f);
        float var = ss * (1.f / 96.f) - mean * mean;
        float rstd = rsqrtf(var + 1e-5f);
        #pragma unroll
        for (int j = 0; j < 6; j++) {
          int nn = j * 16 + l16;
          out2[(size_t)mm * 96 + nn] = f2bf((rv[j] - mean) * rstd * gv[j] + b2v[j]);
        }
      } else {
        #pragma unroll
        for (int j = 0; j < 6; j++) {
          int nn = n0 + j * 16 + l16;
          float v = acc[i][j][r] + bv[j];
          if (MODE == 1) {
            v = 0.5f * v * (1.0f + erff(v * 0.70710678118f));
            ((u16*)outp)[(size_t)mm * N + nn] = f2bf(v);
          } else if (MODE == 3) {
            float rr = bf2f(xres_in[(size_t)mm * 96 + nn]) + v;
            if (f32) ((float*)outp)[sb + nn] = rr;
            else     ((u16*)outp)[sb + nn] = f2bf(rr);
          } else {  // MODE 4
            int sel = nn / 96, hd = (nn - sel * 96) >> 5, cc = nn & 31;
            float scl = (sel == 0) ? 0.17677669529663687f : 1.0f;
            ((u16*)outp)[((size_t)(sel * 3 + hd) * T_TOK + mm) * 32 + cc] = f2bf(v * scl);
          }
        }
      }
    }
  }
}

// ---------------- MFMA flash attention, transposed scores, no in-loop barriers ----------------
// grid = (6, 384): blockIdx.y = wh = win*3+head, blockIdx.x = 64-row q-chunk.
// S^T = mfma(K_frag, Q_frag): lane holds P[q=l16][key=quad*4+r] -> bias/cid are per-lane-row.
// Fixed softmax max (scores provably small); deferred row-sum reduction.
__global__ __launch_bounds__(256) void attn_mfma_kernel(
    const u16* __restrict__ qkv, const u16* __restrict__ b3,
    u16* __restrict__ attnb) {
  __shared__ alignas(16) u16 Ks[344 * 32];    // swizzled: idx = tok*32 + 8*((ch>>3)^(tok&3)) + (ch&7)
  __shared__ alignas(16) u8  cidk[352];
  __shared__ alignas(16) u16 Vt[32 * 352];    // V^T swizzled: idx = ch*352 + 8*((tok>>3)^((ch>>1)&3)) + (tok&7)
  __shared__ alignas(16) u16 Ps[4][512];      // per-wave P tile, swizzled: idx = q*32 + 8*((k>>3)^(q&3)) + (k&7)

  int tid = threadIdx.x;
  int wh = blockIdx.y;
  int head = wh % 3;
  int win = wh / 3;
  int mw = win & 63;
  int m0 = blockIdx.x * 64;
  size_t wbase = (size_t)win * NTOK;

  const u16* qplane = qkv + ((size_t)head * T_TOK + wbase) * 32;
  const u16* kplane = qkv + ((size_t)(3 + head) * T_TOK + wbase) * 32;
  const u16* vplane = qkv + ((size_t)(6 + head) * T_TOK + wbase) * 32;

  // stage K (tok 343 zeroed; rows beyond read OOB into cid/Vt = finite tiny, masked anyway)
  for (int i = tid; i < 1376; i += 256) {
    int tok = i >> 2, cb = i & 3;
    uint4 kv = make_uint4(0, 0, 0, 0);
    if (tok < 343) kv = *(const uint4*)(kplane + (size_t)tok * 32 + cb * 8);
    *(uint4*)&Ks[tok * 32 + 8 * (cb ^ (tok & 3))] = kv;
  }
  // stage V^T with u32 token-pair writes (bank-friendly)
  for (int i = tid; i < 688; i += 256) {
    int p = i >> 2, cb = (i & 3) * 8;
    int t0 = 2 * p;
    uint4 v0 = *(const uint4*)(vplane + (size_t)t0 * 32 + cb);
    uint4 v1 = make_uint4(0, 0, 0, 0);
    if (t0 + 1 < 343) v1 = *(const uint4*)(vplane + (size_t)(t0 + 1) * 32 + cb);
    u32 a0[4] = {v0.x, v0.y, v0.z, v0.w};
    u32 a1[4] = {v1.x, v1.y, v1.z, v1.w};
    int blk = t0 >> 3, tin = (t0 & 7) >> 1;
    #pragma unroll
    for (int q = 0; q < 4; q++) {
      int ch0 = cb + 2 * q;
      u32 w0v = (a0[q] & 0xffffu) | ((a1[q] & 0xffffu) << 16);
      u32 w1v = (a0[q] >> 16) | (a1[q] & 0xffff0000u);
      ((u32*)Vt)[ch0 * 176 + 4 * (blk ^ ((ch0 >> 1) & 3)) + tin] = w0v;
      ((u32*)Vt)[(ch0 + 1) * 176 + 4 * (blk ^ ((ch0 >> 1) & 3)) + tin] = w1v;
    }
  }
  // zero V pad cols 344..351
  {
    int ch = tid >> 3, j = tid & 7;
    if (tid < 256) Vt[ch * 352 + 8 * (43 ^ ((ch >> 1) & 3)) + j] = 0;
  }
  for (int n = tid; n < 352; n += 256) cidk[n] = (n < 343) ? (u8)cid_of(mw, n) : (u8)255;
  __syncthreads();

  int w = tid >> 6, lane = tid & 63, quad = lane >> 4, l16 = lane & 15;
  int qbase = m0 + w * 16;
  int qrow_l = qbase + l16;                       // this lane's q-row (score layout)
  int qc = qrow_l < NTOK ? qrow_l : NTOK - 1;
  s16x8 fq = *(const s16x8*)(qplane + (size_t)qrow_l * 32 + quad * 8);
  int cq = cid_of(mw, qc);
  const u16* b3row = b3 + ((size_t)head * 343 + qc) * 352;

  float lsum = 0.f;
  f32x4 o0 = {0.f, 0.f, 0.f, 0.f}, o1 = {0.f, 0.f, 0.f, 0.f};
  const f32x4 zz = {0.f, 0.f, 0.f, 0.f};
  int swl = l16 & 3;
  int vsw0 = (l16 >> 1) & 3, vsw1 = ((16 + l16) >> 1) & 3;

  for (int t32 = 0; t32 < 11; t32++) {
    #pragma unroll
    for (int h = 0; h < 2; h++) {
      int kb = t32 * 32 + h * 16;
      int ktok = kb + l16;
      s16x8 fk = *(const s16x8*)&Ks[ktok * 32 + 8 * (quad ^ (ktok & 3))];
      f32x4 st = __builtin_amdgcn_mfma_f32_16x16x32_bf16(fk, fq, zz, 0, 0, 0);
      #pragma unroll
      for (int r = 0; r < 4; r++) {
        int key = kb + quad * 4 + r;
        float sv = st[r] + bf2f(b3row[key]) + ((cq == (int)cidk[key]) ? 0.f : -100.f);
        float p = __expf(sv);
        lsum += p;
        int k32 = h * 16 + quad * 4 + r;
        Ps[w][l16 * 32 + 8 * ((k32 >> 3) ^ swl) + (k32 & 7)] = f2bf(p);
      }
    }
    // per-wave private Ps: LDS ops are in-order within a wave -> no barrier needed
    s16x8 fp  = *(const s16x8*)&Ps[w][l16 * 32 + 8 * (quad ^ swl)];
    s16x8 fv0 = *(const s16x8*)&Vt[l16 * 352 + 8 * ((t32 * 4 + quad) ^ vsw0)];
    s16x8 fv1 = *(const s16x8*)&Vt[(16 + l16) * 352 + 8 * ((t32 * 4 + quad) ^ vsw1)];
    o0 = __builtin_amdgcn_mfma_f32_16x16x32_bf16(fp, fv0, o0, 0, 0, 0);
    o1 = __builtin_amdgcn_mfma_f32_16x16x32_bf16(fp, fv1, o1, 0, 0, 0);
  }

  // row sums: reduce across quads, then pull the right row's sum per output reg
  lsum += __shfl_xor(lsum, 16);
  lsum += __shfl_xor(lsum, 32);
  #pragma unroll
  for (int r = 0; r < 4; r++) {
    int qrow = qbase + quad * 4 + r;
    float ls = __shfl(lsum, quad * 4 + r);
    if (qrow < NTOK) {
      float rs = 1.0f / ls;
      size_t ob = (wbase + qrow) * 96 + head * 32;
      attnb[ob + l16] = f2bf(o0[r] * rs);
      attnb[ob + 16 + l16] = f2bf(o1[r] * rs);
    }
  }
}

extern "C" void kernel_launch(void* const* d_in, const int* in_sizes, int n_in,
                              void* d_out, int out_size, void* d_ws, size_t ws_size,
                              hipStream_t stream) {
  (void)in_sizes; (void)n_in; (void)out_size; (void)ws_size;
  const void* x       = d_in[0];
  const void* g1      = d_in[2];
  const void* b1      = d_in[3];
  const void* w_qkv   = d_in[4];
  const void* b_qkv   = d_in[5];
  const void* bias_tb = d_in[6];
  const void* w_proj  = d_in[7];
  const void* b_proj  = d_in[8];
  const void* g2      = d_in[9];
  const void* b2      = d_in[10];
  const void* w_fc1   = d_in[11];
  const void* b_fc1   = d_in[12];
  const void* w_fc2   = d_in[13];
  const void* b_fc2   = d_in[14];
  const int* rel_idx  = (const int*)d_in[15];

  char* ws = (char*)d_ws;
  int*  dflag = (int*)ws;
  u16*  winb  = (u16*)(ws + 256);
  u16*  xresb = (u16*)(ws + 256 + 8429568);
  u16*  qkvb  = (u16*)(ws + 256 + 2 * 8429568);
  u16*  attnb = (u16*)(ws + 256 + 2 * 8429568 + 25288704);
  u16*  h2b   = (u16*)(ws + 256 + 2 * 8429568);
  u16*  b3b   = (u16*)(ws + 256 + 2 * 8429568 + 33718272);
  u16*  wcat  = (u16*)(ws + 256 + 2 * 8429568 + 33718272 + 724416);
  u16*  w_qkvb = wcat;
  u16*  w_projb = wcat + 27648;
  u16*  w_fc1b = wcat + 36864;
  u16*  w_fc2b = wcat + 73728;

  detect_kernel<<<1, 64, 0, stream>>>((const u16*)x, dflag);
  wconv_kernel<<<432, 256, 0, stream>>>(w_qkv, w_proj, w_fc1, w_fc2, wcat, dflag);
  b3_kernel<<<dim3(343, 3), 256, 0, stream>>>(bias_tb, rel_idx, b3b, dflag);
  // 1. LN1 + shift + window partition
  ln_gather_kernel<<<T_TOK / 4, 256, 0, stream>>>(x, g1, b1, winb, dflag);
  // 2. QKV GEMM -> planar qkv (q pre-scaled)
  gemm_mfma_kernel<4><<<dim3(343, 3), 256, 0, stream>>>(
      winb, w_qkvb, b_qkv, nullptr, nullptr, nullptr, nullptr, nullptr, qkvb, 96, 288, dflag);
  // 3. MFMA flash attention -> attnb [T,96]
  attn_mfma_kernel<<<dim3(6, 384), 256, 0, stream>>>(qkvb, b3b, attnb);
  // 4. proj GEMM + shortcut residual -> xresb, fused LN2 -> winb
  gemm_mfma_kernel<2><<<dim3(343, 1), 256, 0, stream>>>(
      attnb, w_projb, b_proj, x, nullptr, g2, b2, winb, xresb, 96, 96, dflag);
  // 5. FC1 + exact GELU -> h2 [T,384]
  gemm_mfma_kernel<1><<<dim3(343, 4), 256, 0, stream>>>(
      winb, w_fc1b, b_fc1, nullptr, nullptr, nullptr, nullptr, nullptr, h2b, 96, 384, dflag);
  // 6. FC2 + residual + scatter to spatial order -> d_out (fp32 if f32 else bf16)
  gemm_mfma_kernel<3><<<dim3(343, 1), 256, 0, stream>>>(
      h2b, w_fc2b, b_fc2, nullptr, xresb, nullptr, nullptr, nullptr, d_out, 384, 96, dflag);
}

// Round 8
// 228.715 us; speedup vs baseline: 13.3008x; 1.1301x over previous
//
#include <hip/hip_runtime.h>
#include <hip/hip_bf16.h>
#include <math.h>

typedef unsigned short u16;
typedef unsigned int u32;
typedef unsigned char u8;

#define T_TOK 43904   // 128 windows * 343 tokens
#define NTOK 343
#define LOG2E 1.4426950408889634f
#define MASKV 144.26950408889634f   // 100 * log2(e)

typedef __attribute__((ext_vector_type(4))) float f32x4;
typedef __attribute__((ext_vector_type(8))) short s16x8;

__device__ __forceinline__ float bf2f(u32 v) { return __uint_as_float(v << 16); }
__device__ __forceinline__ u16 f2bf(float f) {
  u32 u = __float_as_uint(f);
  return (u16)((u + 0x7fffu + ((u >> 16) & 1u)) >> 16);
}

// ---- dual-dtype input loaders: f32!=0 -> data is fp32, else packed bf16 ----
__device__ __forceinline__ float ldf(const void* p, int f32, size_t i) {
  return f32 ? ((const float*)p)[i] : bf2f(((const u16*)p)[i]);
}
__device__ __forceinline__ float2 ld2(const void* p, int f32, size_t i) {  // i even
  if (f32) return *(const float2*)((const float*)p + i);
  u32 pk = *(const u32*)((const u16*)p + i);
  return make_float2(bf2f(pk & 0xffff), bf2f(pk >> 16));
}

// token index t (window-major) -> element offset of the (b,d,h,w) voxel in x/out
__device__ __forceinline__ size_t spatial_base(int t) {
  int win = t / 343, n = t - win * 343;
  int bb = win >> 6, wrem = win & 63;
  int wd = wrem >> 4, wh = (wrem >> 2) & 3, ww = wrem & 3;
  int td = n / 49; int r = n - td * 49; int th = r / 7; int tw = r - th * 7;
  int d0 = wd * 7 + td + 3; if (d0 >= 28) d0 -= 28;
  int h0 = wh * 7 + th + 3; if (h0 >= 28) h0 -= 28;
  int w0 = ww * 7 + tw + 3; if (w0 >= 28) w0 -= 28;
  return (size_t)(((bb * 28 + d0) * 28 + h0) * 28 + w0) * 96;
}

// shifted-window mask region id (exact reproduction of MONAI compute_mask)
__device__ __forceinline__ int zone3(int p) { return p < 21 ? 0 : (p < 25 ? 1 : 2); }
__device__ __forceinline__ int cid_of(int mw, int n) {
  int td = n / 49, rr = n - td * 49, th = rr / 7, tw = rr - th * 7;
  int d = (mw >> 4) * 7 + td, h = ((mw >> 2) & 3) * 7 + th, w = (mw & 3) * 7 + tw;
  return zone3(d) * 9 + zone3(h) * 3 + zone3(w);
}

// ---------------- dtype detector ----------------
__global__ __launch_bounds__(64) void detect_kernel(const u16* __restrict__ x, int* __restrict__ flag) {
  int lane = threadIdx.x;
  int bad = 0;
  #pragma unroll
  for (int q = 0; q < 8; q++) {
    u16 b = x[(lane * 8 + q) * 2];
    int e = (b >> 7) & 0xff;
    if (e >= 0x90) bad = 1;
  }
  unsigned long long m = __ballot(bad);
  if (lane == 0) *flag = (m != 0ull) ? 1 : 0;
}

// ---------------- weight conversion -> bf16 [n][k] concat ----------------
__global__ __launch_bounds__(256) void wconv_kernel(
    const void* __restrict__ w0, const void* __restrict__ w1,
    const void* __restrict__ w2, const void* __restrict__ w3,
    u16* __restrict__ out, const int* __restrict__ dflag) {
  int f32 = __builtin_amdgcn_readfirstlane(dflag[0]);
  int g = blockIdx.x * 256 + threadIdx.x;
  if (g >= 110592) return;
  float v;
  if (g < 27648)      v = ldf(w0, f32, g);
  else if (g < 36864) v = ldf(w1, f32, g - 27648);
  else if (g < 73728) v = ldf(w2, f32, g - 36864);
  else                v = ldf(w3, f32, g - 73728);
  out[g] = f2bf(v);
}

// ---------------- LN1 + shift + window partition gather ----------------
__global__ __launch_bounds__(256) void ln_gather_kernel(
    const void* __restrict__ x, const void* __restrict__ g, const void* __restrict__ b,
    u16* __restrict__ outw, const int* __restrict__ dflag) {
  int f32 = __builtin_amdgcn_readfirstlane(dflag[0]);
  int t = blockIdx.x * 4 + (threadIdx.x >> 6);
  int lane = threadIdx.x & 63;
  size_t base = spatial_base(t);
  int c = lane * 2;
  float vx = 0.f, vy = 0.f;
  if (c < 96) { float2 p = ld2(x, f32, base + c); vx = p.x; vy = p.y; }
  float s = vx + vy, ss = vx * vx + vy * vy;
  #pragma unroll
  for (int o = 1; o < 64; o <<= 1) { s += __shfl_xor(s, o); ss += __shfl_xor(ss, o); }
  float mean = s * (1.f / 96.f);
  float var = ss * (1.f / 96.f) - mean * mean;
  float rstd = rsqrtf(var + 1e-5f);
  if (c < 96) {
    float2 gp = ld2(g, f32, c), bp = ld2(b, f32, c);
    float y0 = (vx - mean) * rstd * gp.x + bp.x;
    float y1 = (vy - mean) * rstd * gp.y + bp.y;
    *(u32*)(outw + (size_t)t * 96 + c) = (u32)f2bf(y0) | ((u32)f2bf(y1) << 16);
  }
}

// ---------------- B3M: (bias + mask) * log2e, per window-class ----------------
// b3m[cls][head][row][col 352]; cls bit2=wd==3, bit1=wh==3, bit0=ww==3.
__global__ __launch_bounds__(256) void b3m_kernel(
    const void* __restrict__ bias_table, const int* __restrict__ rel,
    u16* __restrict__ b3m, const int* __restrict__ dflag) {
  int f32 = __builtin_amdgcn_readfirstlane(dflag[0]);
  int row = blockIdx.x;
  int by = blockIdx.y;            // cls*3 + head
  int cls = by / 3, head = by - cls * 3;
  int mw = ((cls & 4) ? 48 : 0) | ((cls & 2) ? 12 : 0) | ((cls & 1) ? 3 : 0);
  int cidq = cid_of(mw, row);
  for (int col = threadIdx.x; col < 352; col += 256) {
    float v = -MASKV;
    if (col < 343) {
      v = ldf(bias_table, f32, (size_t)rel[row * 343 + col] * 3 + head) * LOG2E;
      if (cid_of(mw, col) != cidq) v -= MASKV;
    }
    b3m[((size_t)by * 343 + row) * 352 + col] = f2bf(v);
  }
}

// ---------------- QKV MFMA GEMM -> planar [sel*3+head][tok][32] ----------------
// grid = (343, 3), block = 256. q-plane scaled by log2e/sqrt(32).
__global__ __launch_bounds__(256) void qkv_kernel(
    const u16* __restrict__ A, const u16* __restrict__ Wb, const void* __restrict__ bias,
    u16* __restrict__ outp, const int* __restrict__ dflag) {
  int f32 = __builtin_amdgcn_readfirstlane(dflag[0]);
  __shared__ alignas(16) u16 As[128 * 104];
  __shared__ alignas(16) u16 Ws[96 * 104];
  int tid = threadIdx.x;
  int m0 = blockIdx.x * 128, n0 = blockIdx.y * 96;
  int w = tid >> 6, lane = tid & 63, quad = lane >> 4, l16 = lane & 15;
  f32x4 acc[2][6];
  #pragma unroll
  for (int i = 0; i < 2; i++)
    #pragma unroll
    for (int j = 0; j < 6; j++) acc[i][j] = (f32x4){0.f, 0.f, 0.f, 0.f};
  for (int i = tid; i < 1536; i += 256) {
    int row = i / 12; int c = (i - row * 12) * 8;
    *(uint4*)&As[row * 104 + c] = *(const uint4*)(A + (size_t)(m0 + row) * 96 + c);
  }
  for (int i = tid; i < 1152; i += 256) {
    int row = i / 12; int c = (i - row * 12) * 8;
    *(uint4*)&Ws[row * 104 + c] = *(const uint4*)(Wb + (size_t)(n0 + row) * 96 + c);
  }
  __syncthreads();
  #pragma unroll
  for (int kc = 0; kc < 3; kc++) {
    s16x8 fa0 = *(const s16x8*)&As[(w * 32 + l16) * 104 + kc * 32 + quad * 8];
    s16x8 fa1 = *(const s16x8*)&As[(w * 32 + 16 + l16) * 104 + kc * 32 + quad * 8];
    #pragma unroll
    for (int j = 0; j < 6; j++) {
      s16x8 fb = *(const s16x8*)&Ws[(j * 16 + l16) * 104 + kc * 32 + quad * 8];
      acc[0][j] = __builtin_amdgcn_mfma_f32_16x16x32_bf16(fa0, fb, acc[0][j], 0, 0, 0);
      acc[1][j] = __builtin_amdgcn_mfma_f32_16x16x32_bf16(fa1, fb, acc[1][j], 0, 0, 0);
    }
  }
  #pragma unroll
  for (int i = 0; i < 2; i++) {
    #pragma unroll
    for (int r = 0; r < 4; r++) {
      int mm = m0 + w * 32 + i * 16 + quad * 4 + r;
      #pragma unroll
      for (int j = 0; j < 6; j++) {
        int nn = n0 + j * 16 + l16;
        float v = acc[i][j][r] + ldf(bias, f32, nn);
        int sel = nn / 96, hd = (nn - sel * 96) >> 5, cc = nn & 31;
        float scl = (sel == 0) ? 0.25504208f : 1.0f;   // log2e / sqrt(32)
        outp[((size_t)(sel * 3 + hd) * T_TOK + mm) * 32 + cc] = f2bf(v * scl);
      }
    }
  }
}

// ---------------- MFMA flash attention v3 ----------------
// grid = (3, 384), block = 512 (8 waves, 16 q-rows each; 128 q-rows/block).
__device__ __forceinline__ int vsw(int ch) { return ((ch >> 1) ^ (ch >> 3)) & 3; }

__global__ __launch_bounds__(512) void attn_mfma_kernel(
    const u16* __restrict__ qkv, const u16* __restrict__ b3m,
    u16* __restrict__ attnb) {
  __shared__ alignas(16) u16 Ks[352 * 32];   // idx = tok*32 + 8*((ch>>3)^(tok&3)) + (ch&7)
  __shared__ alignas(16) u16 Vt[32 * 352];   // idx = ch*352 + 8*((tok>>3)^vsw(ch)) + (tok&7)
  __shared__ alignas(16) u16 Ps[8][512];     // idx = q*32 + 8*((k32>>3)^swl(q)) + (k32&7)

  int tid = threadIdx.x;
  int wh = blockIdx.y;
  int head = wh % 3;
  int win = wh / 3;
  int mw = win & 63;
  int cls = (((mw >> 4) == 3) ? 4 : 0) | ((((mw >> 2) & 3) == 3) ? 2 : 0) | (((mw & 3) == 3) ? 1 : 0);
  int m0 = blockIdx.x * 128;
  size_t wbase = (size_t)win * NTOK;

  const u16* qplane = qkv + ((size_t)head * T_TOK + wbase) * 32;
  const u16* kplane = qkv + ((size_t)(3 + head) * T_TOK + wbase) * 32;
  const u16* vplane = qkv + ((size_t)(6 + head) * T_TOK + wbase) * 32;

  // stage K rows 0..351 (343+ zero)
  for (int i = tid; i < 1408; i += 512) {
    int tok = i >> 2, cb = i & 3;
    uint4 kv = make_uint4(0, 0, 0, 0);
    if (tok < 343) kv = *(const uint4*)(kplane + (size_t)tok * 32 + cb * 8);
    *(uint4*)&Ks[tok * 32 + 8 * (cb ^ (tok & 3))] = kv;
  }
  // stage V^T (token-pair u32 writes, conflict-free swizzle)
  for (int i = tid; i < 688; i += 512) {
    int p = i >> 2, cb = (i & 3) * 8;
    int t0 = 2 * p;
    uint4 v0 = *(const uint4*)(vplane + (size_t)t0 * 32 + cb);
    uint4 v1 = make_uint4(0, 0, 0, 0);
    if (t0 + 1 < 343) v1 = *(const uint4*)(vplane + (size_t)(t0 + 1) * 32 + cb);
    u32 a0[4] = {v0.x, v0.y, v0.z, v0.w};
    u32 a1[4] = {v1.x, v1.y, v1.z, v1.w};
    int blk = t0 >> 3, tin = (t0 & 7) >> 1;
    #pragma unroll
    for (int q = 0; q < 4; q++) {
      int ch0 = cb + 2 * q;
      u32 w0v = (a0[q] & 0xffffu) | ((a1[q] & 0xffffu) << 16);
      u32 w1v = (a0[q] >> 16) | (a1[q] & 0xffff0000u);
      ((u32*)Vt)[ch0 * 176 + 4 * (blk ^ vsw(ch0)) + tin] = w0v;
      ((u32*)Vt)[(ch0 + 1) * 176 + 4 * (blk ^ vsw(ch0 + 1)) + tin] = w1v;
    }
  }
  // zero V^T pad toks 344..351 (blk 43)
  if (tid < 256) {
    int ch = tid >> 3, j = tid & 7;
    Vt[ch * 352 + 8 * (43 ^ vsw(ch)) + j] = 0;
  }
  __syncthreads();

  int w = tid >> 6, lane = tid & 63, quad = lane >> 4, l16 = lane & 15;
  int qbase = m0 + w * 16;
  int qrow_l = qbase + l16;
  int qc = qrow_l < NTOK ? qrow_l : NTOK - 1;
  s16x8 fq = *(const s16x8*)(qplane + (size_t)qc * 32 + quad * 8);
  const u16* bmrow = b3m + ((size_t)(cls * 3 + head) * 343 + qc) * 352;
  int swl = (l16 ^ (l16 >> 2)) & 3;
  int vsw0 = vsw(l16), vsw1 = vsw(16 + l16);

  float lsum = 0.f;
  f32x4 o0 = {0.f, 0.f, 0.f, 0.f}, o1 = {0.f, 0.f, 0.f, 0.f};
  const f32x4 zz = {0.f, 0.f, 0.f, 0.f};

  for (int t32 = 0; t32 < 11; t32++) {
    #pragma unroll
    for (int h = 0; h < 2; h++) {
      int kb = t32 * 32 + h * 16;
      int ktok = kb + l16;
      s16x8 fk = *(const s16x8*)&Ks[ktok * 32 + 8 * (quad ^ (ktok & 3))];
      f32x4 st = __builtin_amdgcn_mfma_f32_16x16x32_bf16(fk, fq, zz, 0, 0, 0);
      uint2 bm = *(const uint2*)(bmrow + kb + quad * 4);
      float p0 = exp2f(st[0] + bf2f(bm.x & 0xffff));
      float p1 = exp2f(st[1] + bf2f(bm.x >> 16));
      float p2 = exp2f(st[2] + bf2f(bm.y & 0xffff));
      float p3 = exp2f(st[3] + bf2f(bm.y >> 16));
      lsum += (p0 + p1) + (p2 + p3);
      u32 pa = (__float_as_uint(p0) >> 16) | (__float_as_uint(p1) & 0xffff0000u);
      u32 pb = (__float_as_uint(p2) >> 16) | (__float_as_uint(p3) & 0xffff0000u);
      int blkp = h * 2 + (quad >> 1);
      *(uint2*)&Ps[w][l16 * 32 + 8 * (blkp ^ swl) + (quad & 1) * 4] = make_uint2(pa, pb);
    }
    // per-wave private Ps: wave-internal LDS ordering, no barrier
    s16x8 fp  = *(const s16x8*)&Ps[w][l16 * 32 + 8 * (quad ^ swl)];
    s16x8 fv0 = *(const s16x8*)&Vt[l16 * 352 + 8 * ((t32 * 4 + quad) ^ vsw0)];
    s16x8 fv1 = *(const s16x8*)&Vt[(16 + l16) * 352 + 8 * ((t32 * 4 + quad) ^ vsw1)];
    o0 = __builtin_amdgcn_mfma_f32_16x16x32_bf16(fp, fv0, o0, 0, 0, 0);
    o1 = __builtin_amdgcn_mfma_f32_16x16x32_bf16(fp, fv1, o1, 0, 0, 0);
  }

  lsum += __shfl_xor(lsum, 16);
  lsum += __shfl_xor(lsum, 32);
  #pragma unroll
  for (int r = 0; r < 4; r++) {
    int qrow = qbase + quad * 4 + r;
    float ls = __shfl(lsum, quad * 4 + r);
    if (qrow < NTOK) {
      float rs = 1.0f / ls;
      size_t ob = (wbase + qrow) * 96 + head * 32;
      attnb[ob + l16] = f2bf(o0[r] * rs);
      attnb[ob + 16 + l16] = f2bf(o1[r] * rs);
    }
  }
}

// ---------------- mega-fused MLP: proj+res+LN2+FC1+GELU+FC2+res+scatter ----------------
// grid = 686 (64 rows/block), block = 256 (4 waves x 16 rows).
__global__ __launch_bounds__(256) void mlp_fused_kernel(
    const u16* __restrict__ attnb, const u16* __restrict__ wcat,
    const void* __restrict__ x, const void* __restrict__ b_proj,
    const void* __restrict__ g2, const void* __restrict__ b2,
    const void* __restrict__ b_fc1, const void* __restrict__ b_fc2,
    void* __restrict__ outp, const int* __restrict__ dflag) {
  int f32 = __builtin_amdgcn_readfirstlane(dflag[0]);
  __shared__ alignas(16) u16 As[64 * 104];
  __shared__ alignas(16) u16 As2[64 * 104];
  __shared__ alignas(16) u16 Ws[96 * 104];
  const u16* w_projb = wcat + 27648;
  const u16* w_fc1b  = wcat + 36864;
  const u16* w_fc2b  = wcat + 73728;
  int tid = threadIdx.x, m0 = blockIdx.x * 64;
  int w = tid >> 6, lane = tid & 63, quad = lane >> 4, l16 = lane & 15;

  // stage attn rows + w_proj
  for (int i = tid; i < 768; i += 256) {
    int row = i / 12, c = (i - row * 12) * 8;
    *(uint4*)&As[row * 104 + c] = *(const uint4*)(attnb + (size_t)(m0 + row) * 96 + c);
  }
  for (int i = tid; i < 1152; i += 256) {
    int row = i / 12, c = (i - row * 12) * 8;
    *(uint4*)&Ws[row * 104 + c] = *(const uint4*)(w_projb + row * 96 + c);
  }
  __syncthreads();
  f32x4 accp[6];
  #pragma unroll
  for (int j = 0; j < 6; j++) accp[j] = (f32x4){0.f, 0.f, 0.f, 0.f};
  #pragma unroll
  for (int kc = 0; kc < 3; kc++) {
    s16x8 fa = *(const s16x8*)&As[(w * 16 + l16) * 104 + kc * 32 + quad * 8];
    #pragma unroll
    for (int j = 0; j < 6; j++) {
      s16x8 fb = *(const s16x8*)&Ws[(j * 16 + l16) * 104 + kc * 32 + quad * 8];
      accp[j] = __builtin_amdgcn_mfma_f32_16x16x32_bf16(fa, fb, accp[j], 0, 0, 0);
    }
  }
  __syncthreads();   // all waves done reading As/Ws before overwrite

  // epilogue 1: + b_proj + x -> rv ; LN2 -> As (own-wave slab)
  float bp[6], gv[6], b2v[6];
  #pragma unroll
  for (int j = 0; j < 6; j++) {
    int nn = j * 16 + l16;
    bp[j] = ldf(b_proj, f32, nn); gv[j] = ldf(g2, f32, nn); b2v[j] = ldf(b2, f32, nn);
  }
  float rv[4][6];
  size_t sb[4];
  #pragma unroll
  for (int r = 0; r < 4; r++) {
    int mm = m0 + w * 16 + quad * 4 + r;
    sb[r] = spatial_base(mm);
    float s = 0.f, ss = 0.f;
    #pragma unroll
    for (int j = 0; j < 6; j++) {
      float v = accp[j][r] + bp[j] + ldf(x, f32, sb[r] + j * 16 + l16);
      rv[r][j] = v; s += v; ss += v * v;
    }
    #pragma unroll
    for (int o = 1; o < 16; o <<= 1) { s += __shfl_xor(s, o); ss += __shfl_xor(ss, o); }
    float mean = s * (1.f / 96.f);
    float var = ss * (1.f / 96.f) - mean * mean;
    float rstd = rsqrtf(var + 1e-5f);
    #pragma unroll
    for (int j = 0; j < 6; j++)
      As[(w * 16 + quad * 4 + r) * 104 + j * 16 + l16] = f2bf((rv[r][j] - mean) * rstd * gv[j] + b2v[j]);
  }

  f32x4 acc2[6];
  #pragma unroll
  for (int j = 0; j < 6; j++) acc2[j] = (f32x4){0.f, 0.f, 0.f, 0.f};
  for (int c = 0; c < 4; c++) {
    __syncthreads();
    for (int i = tid; i < 1152; i += 256) {
      int row = i / 12, cc = (i - row * 12) * 8;
      *(uint4*)&Ws[row * 104 + cc] = *(const uint4*)(w_fc1b + (size_t)(96 * c + row) * 96 + cc);
    }
    __syncthreads();
    f32x4 a1[6];
    #pragma unroll
    for (int j = 0; j < 6; j++) a1[j] = (f32x4){0.f, 0.f, 0.f, 0.f};
    #pragma unroll
    for (int kc = 0; kc < 3; kc++) {
      s16x8 fa = *(const s16x8*)&As[(w * 16 + l16) * 104 + kc * 32 + quad * 8];
      #pragma unroll
      for (int j = 0; j < 6; j++) {
        s16x8 fb = *(const s16x8*)&Ws[(j * 16 + l16) * 104 + kc * 32 + quad * 8];
        a1[j] = __builtin_amdgcn_mfma_f32_16x16x32_bf16(fa, fb, a1[j], 0, 0, 0);
      }
    }
    #pragma unroll
    for (int j = 0; j < 6; j++) {
      float bf1 = ldf(b_fc1, f32, 96 * c + j * 16 + l16);
      #pragma unroll
      for (int r = 0; r < 4; r++) {
        float v = a1[j][r] + bf1;
        v = 0.5f * v * (1.0f + erff(v * 0.70710678118f));
        As2[(w * 16 + quad * 4 + r) * 104 + j * 16 + l16] = f2bf(v);
      }
    }
    __syncthreads();
    for (int i = tid; i < 1152; i += 256) {
      int row = i / 12, cc = (i - row * 12) * 8;
      *(uint4*)&Ws[row * 104 + cc] = *(const uint4*)(w_fc2b + (size_t)row * 384 + 96 * c + cc);
    }
    __syncthreads();
    #pragma unroll
    for (int kc = 0; kc < 3; kc++) {
      s16x8 fa2 = *(const s16x8*)&As2[(w * 16 + l16) * 104 + kc * 32 + quad * 8];
      #pragma unroll
      for (int j = 0; j < 6; j++) {
        s16x8 fb = *(const s16x8*)&Ws[(j * 16 + l16) * 104 + kc * 32 + quad * 8];
        acc2[j] = __builtin_amdgcn_mfma_f32_16x16x32_bf16(fa2, fb, acc2[j], 0, 0, 0);
      }
    }
  }
  // final: + b_fc2 + rv -> out at spatial location
  float bf2v[6];
  #pragma unroll
  for (int j = 0; j < 6; j++) bf2v[j] = ldf(b_fc2, f32, j * 16 + l16);
  #pragma unroll
  for (int r = 0; r < 4; r++) {
    #pragma unroll
    for (int j = 0; j < 6; j++) {
      float v = acc2[j][r] + bf2v[j] + rv[r][j];
      if (f32) ((float*)outp)[sb[r] + j * 16 + l16] = v;
      else     ((u16*)outp)[sb[r] + j * 16 + l16] = f2bf(v);
    }
  }
}

extern "C" void kernel_launch(void* const* d_in, const int* in_sizes, int n_in,
                              void* d_out, int out_size, void* d_ws, size_t ws_size,
                              hipStream_t stream) {
  (void)in_sizes; (void)n_in; (void)out_size; (void)ws_size;
  const void* x       = d_in[0];
  const void* g1      = d_in[2];
  const void* b1      = d_in[3];
  const void* w_qkv   = d_in[4];
  const void* b_qkv   = d_in[5];
  const void* bias_tb = d_in[6];
  const void* w_proj  = d_in[7];
  const void* b_proj  = d_in[8];
  const void* g2      = d_in[9];
  const void* b2      = d_in[10];
  const void* w_fc1   = d_in[11];
  const void* b_fc1   = d_in[12];
  const void* w_fc2   = d_in[13];
  const void* b_fc2   = d_in[14];
  const int* rel_idx  = (const int*)d_in[15];

  // workspace (~48.2 MB): dflag | winb 8.43M | qkvb 25.3M | attnb 8.43M | b3m 5.80M | wcat 0.22M
  char* ws = (char*)d_ws;
  int*  dflag = (int*)ws;
  u16*  winb  = (u16*)(ws + 256);
  u16*  qkvb  = (u16*)(ws + 8429824);
  u16*  attnb = (u16*)(ws + 33718528);
  u16*  b3mb  = (u16*)(ws + 42148096);
  u16*  wcat  = (u16*)(ws + 47943424);
  u16*  w_qkvb = wcat;

  detect_kernel<<<1, 64, 0, stream>>>((const u16*)x, dflag);
  wconv_kernel<<<432, 256, 0, stream>>>(w_qkv, w_proj, w_fc1, w_fc2, wcat, dflag);
  b3m_kernel<<<dim3(343, 24), 256, 0, stream>>>(bias_tb, rel_idx, b3mb, dflag);
  // 1. LN1 + shift + window partition
  ln_gather_kernel<<<T_TOK / 4, 256, 0, stream>>>(x, g1, b1, winb, dflag);
  // 2. QKV GEMM -> planar qkv (q pre-scaled by log2e/sqrt(32))
  qkv_kernel<<<dim3(343, 3), 256, 0, stream>>>(winb, w_qkvb, b_qkv, qkvb, dflag);
  // 3. flash attention -> attnb
  attn_mfma_kernel<<<dim3(3, 384), 512, 0, stream>>>(qkvb, b3mb, attnb);
  // 4. proj + residual + LN2 + FC1 + GELU + FC2 + residual + scatter -> d_out
  mlp_fused_kernel<<<686, 256, 0, stream>>>(attnb, wcat, x, b_proj, g2, b2,
                                            b_fc1, b_fc2, d_out, dflag);
}